// Round 3
// baseline (8571.618 us; speedup 1.0000x reference)
//
#include <hip/hip_runtime.h>
#include <hip/hip_bf16.h>
#include <math.h>

typedef short short8 __attribute__((ext_vector_type(8)));
typedef float floatx4 __attribute__((ext_vector_type(4)));

#define DEV static __device__ __forceinline__

DEV float s2f(short v) {
    unsigned int u = ((unsigned int)(unsigned short)v) << 16;
    float f;
    __builtin_memcpy(&f, &u, 4);
    return f;
}
DEV short f2s(float f) {
    __hip_bfloat16 b = __float2bfloat16(f);   // RNE
    short s;
    __builtin_memcpy(&s, &b, 2);
    return s;
}

// ---------------------------------------------------------------------------
// Generic MFMA GEMM: C[M][N] = epi(A[M][K] @ B + bias [+ R])
//   BT=0: B is [K][N] row-major (weights, V)        -> transpose-staged to LDS
//   BT=1: B is [N][K] row-major (K-matrix for QK^T) -> direct-staged
//   EPI=0: plain   EPI=1: exact GELU   EPI=2: add residual R[M][N]
//   AF/BF: A/B source dtype is fp32 (global inputs) vs bf16 (ws activations)
// Block: 256 threads = 4 waves, 64x64 tile, wave w owns rows [16w,16w+16).
// ---------------------------------------------------------------------------
template<int EPI, int BT, int AF, int BF>
__global__ __launch_bounds__(256) void gemm_mfma(
    const void* __restrict__ Av, long long sA,
    const void* __restrict__ Bv, long long sB,
    const float* __restrict__ bias,
    const short* __restrict__ R, long long sR,
    short* __restrict__ C, long long sC,
    int M, int N, int K)
{
    const int bz = blockIdx.z;
    const char* Ac = (const char*)Av + (long long)bz * sA * (AF ? 4 : 2);
    const char* Bc = (const char*)Bv + (long long)bz * sB * (BF ? 4 : 2);
    C += bz * sC;
    if constexpr (EPI == 2) R += bz * sR;

    const int tileM = blockIdx.x * 64;
    const int tileN = blockIdx.y * 64;

    __shared__ short Al[64][40];   // [m][k], padded stride 40 to spread banks
    __shared__ short Bl[64][40];   // [n][k]

    const int tid  = threadIdx.x;
    const int lane = tid & 63;
    const int wave = tid >> 6;

    floatx4 acc[4] = { {0,0,0,0}, {0,0,0,0}, {0,0,0,0}, {0,0,0,0} };

    const int KT = (K + 31) / 32;
    const bool kvec = ((K & 7) == 0);

    for (int kt = 0; kt < KT; ++kt) {
        const int k0 = kt * 32;
        // ---- stage A tile: thread -> row r, 8 contiguous k ----
        {
            const int r  = tid >> 2;
            const int c0 = (tid & 3) * 8;
            const int gm = tileM + r;
            const int gk = k0 + c0;
            short8 v;
            if constexpr (AF) {
                const float* Ap = (const float*)Ac + (long long)gm * K;
                if (kvec && gm < M && gk + 8 <= K) {
                    floatx4 f0 = *(const floatx4*)(Ap + gk);
                    floatx4 f1 = *(const floatx4*)(Ap + gk + 4);
                    for (int j = 0; j < 4; ++j) {
                        ((short*)&v)[j]     = f2s(f0[j]);
                        ((short*)&v)[4 + j] = f2s(f1[j]);
                    }
                } else {
                    for (int j = 0; j < 8; ++j)
                        ((short*)&v)[j] = (gm < M && gk + j < K) ? f2s(Ap[gk + j]) : (short)0;
                }
            } else {
                const short* Ap = (const short*)Ac + (long long)gm * K;
                if (kvec && gm < M && gk + 8 <= K) {
                    v = *(const short8*)(Ap + gk);
                } else {
                    for (int j = 0; j < 8; ++j)
                        ((short*)&v)[j] = (gm < M && gk + j < K) ? Ap[gk + j] : (short)0;
                }
            }
            *(short8*)&Al[r][c0] = v;
        }
        // ---- stage B tile into [n][k] ----
        if constexpr (BT == 1) {
            const int r  = tid >> 2;
            const int c0 = (tid & 3) * 8;
            const int gn = tileN + r;
            const int gk = k0 + c0;
            short8 v;
            if constexpr (BF) {
                const float* Bp = (const float*)Bc + (long long)gn * K;
                for (int j = 0; j < 8; ++j)
                    ((short*)&v)[j] = (gn < N && gk + j < K) ? f2s(Bp[gk + j]) : (short)0;
            } else {
                const short* Bp = (const short*)Bc + (long long)gn * K;
                if (kvec && gn < N && gk + 8 <= K) {
                    v = *(const short8*)(Bp + gk);
                } else {
                    for (int j = 0; j < 8; ++j)
                        ((short*)&v)[j] = (gn < N && gk + j < K) ? Bp[gk + j] : (short)0;
                }
            }
            *(short8*)&Bl[r][c0] = v;
        } else {
            const int n  = tid & 63;      // lanes consecutive in n -> coalesced
            const int kg = tid >> 6;
            const int gn = tileN + n;
            short8 v;
            for (int j = 0; j < 8; ++j) {
                const int gk = k0 + kg * 8 + j;
                const bool ok = (gn < N && gk < K);
                short sv = 0;
                if (ok) {
                    if constexpr (BF) sv = f2s(((const float*)Bc)[(long long)gk * N + gn]);
                    else              sv = ((const short*)Bc)[(long long)gk * N + gn];
                }
                ((short*)&v)[j] = sv;
            }
            *(short8*)&Bl[n][kg * 8] = v;
        }
        __syncthreads();

        // ---- MFMA: wave computes 16x64 strip ----
        const int mrow = wave * 16 + (lane & 15);
        const int koff = (lane >> 4) * 8;
        const short8 af = *(const short8*)&Al[mrow][koff];
        for (int ct = 0; ct < 4; ++ct) {
            const short8 bfrag = *(const short8*)&Bl[ct * 16 + (lane & 15)][koff];
            acc[ct] = __builtin_amdgcn_mfma_f32_16x16x32_bf16(af, bfrag, acc[ct], 0, 0, 0);
        }
        __syncthreads();
    }

    // ---- epilogue: D row=(lane>>4)*4+r, col=lane&15 ----
    const int col0  = lane & 15;
    const int rbase = (lane >> 4) * 4;
    for (int ct = 0; ct < 4; ++ct) {
        const int gc = tileN + ct * 16 + col0;
        if (gc >= N) continue;
        const float bv = bias ? bias[gc] : 0.0f;
        for (int r = 0; r < 4; ++r) {
            const int gr = tileM + wave * 16 + rbase + r;
            if (gr >= M) continue;
            float v = acc[ct][r] + bv;
            if constexpr (EPI == 1) v = 0.5f * v * (1.0f + erff(v * 0.70710678118654752f));
            if constexpr (EPI == 2) v += s2f(R[(long long)gr * N + gc]);
            C[(long long)gr * N + gc] = f2s(v);
        }
    }
}

// ---------------------------------------------------------------------------
// assemble: H[b][t][d] = (t==0 ? cls[d] : P[b*196+t-1][d]) + pos[t][d]
// P is bf16 (ws); cls/pos are fp32 inputs.
// ---------------------------------------------------------------------------
__global__ __launch_bounds__(256) void assemble_k(
    const short* __restrict__ P, const float* __restrict__ cls,
    const float* __restrict__ pos, short* __restrict__ H)
{
    const long long idx = (long long)blockIdx.x * 256 + threadIdx.x;
    if (idx >= 32LL * 197 * 768) return;
    const int d = (int)(idx % 768);
    const int t = (int)((idx / 768) % 197);
    const long long b = idx / (768LL * 197);
    float v = (t == 0) ? cls[d]
                       : s2f(P[(b * 196 + t - 1) * 768 + d]);
    v += pos[t * 768 + d];
    H[idx] = f2s(v);
}

// ---------------------------------------------------------------------------
// softmax over last dim (n=197 <= 256), in-place bf16, with scale on logits
// ---------------------------------------------------------------------------
__global__ __launch_bounds__(256) void softmax_k(short* __restrict__ S, float scale)
{
    short* s = S + (long long)blockIdx.x * 197;
    const int tid = threadIdx.x;
    __shared__ float red[256];

    float x = 0.0f;
    float v = -1e30f;
    if (tid < 197) { x = s2f(s[tid]) * scale; v = x; }
    red[tid] = v;
    __syncthreads();
    for (int st = 128; st > 0; st >>= 1) {
        if (tid < st) red[tid] = fmaxf(red[tid], red[tid + st]);
        __syncthreads();
    }
    const float mx = red[0];
    __syncthreads();
    const float e = (tid < 197) ? expf(x - mx) : 0.0f;
    red[tid] = e;
    __syncthreads();
    for (int st = 128; st > 0; st >>= 1) {
        if (tid < st) red[tid] += red[tid + st];
        __syncthreads();
    }
    const float inv = 1.0f / red[0];
    if (tid < 197) s[tid] = f2s(e * inv);
}

// ---------------------------------------------------------------------------
// LayerNorm over 768, one block per row. X/Y bf16 ws; g/be fp32 inputs.
// ---------------------------------------------------------------------------
__global__ __launch_bounds__(256) void ln_k(
    const short* __restrict__ X, long long xs,
    short* __restrict__ Y, long long ys,
    const float* __restrict__ g, const float* __restrict__ be)
{
    const short* x = X + (long long)blockIdx.x * xs;
    short* y = Y + (long long)blockIdx.x * ys;
    const int tid = threadIdx.x;

    float v[3], s = 0.0f, sq = 0.0f;
    for (int i = 0; i < 3; ++i) {
        const float t = s2f(x[tid + 256 * i]);
        v[i] = t; s += t; sq += t * t;
    }
    __shared__ float r1[256], r2[256];
    r1[tid] = s; r2[tid] = sq;
    __syncthreads();
    for (int st = 128; st > 0; st >>= 1) {
        if (tid < st) { r1[tid] += r1[tid + st]; r2[tid] += r2[tid + st]; }
        __syncthreads();
    }
    const float m   = r1[0] * (1.0f / 768.0f);
    const float var = r2[0] * (1.0f / 768.0f) - m * m;
    const float rs  = rsqrtf(var + 1e-5f);
    for (int i = 0; i < 3; ++i) {
        const int d = tid + 256 * i;
        y[d] = f2s((v[i] - m) * rs * g[d] + be[d]);
    }
}

// ---------------------------------------------------------------------------
// head: out[b][c] = hc[b] . head_w[:,c] + head_b[c]   (M=32, N=1000, K=768)
// hc bf16 ws; W/hb fp32 inputs; out fp32 (reference output dtype).
// ---------------------------------------------------------------------------
__global__ __launch_bounds__(256) void head_k(
    const short* __restrict__ hc, const float* __restrict__ W,
    const float* __restrict__ hb, float* __restrict__ out)
{
    const int b = blockIdx.x;
    const int tid = threadIdx.x;
    __shared__ float h[768];
    for (int i = tid; i < 768; i += 256) h[i] = s2f(hc[b * 768 + i]);
    __syncthreads();
    for (int c = tid; c < 1000; c += 256) {
        float acc = hb[c];
        for (int k = 0; k < 768; ++k)
            acc += h[k] * W[k * 1000 + c];
        out[b * 1000 + c] = acc;   // fp32 store — reference output dtype is float32
    }
}

// ---------------------------------------------------------------------------
extern "C" void kernel_launch(void* const* d_in, const int* in_sizes, int n_in,
                              void* d_out, int out_size, void* d_ws, size_t ws_size,
                              hipStream_t stream)
{
    const float* x     = (const float*)d_in[0];
    const float* cls   = (const float*)d_in[1];
    const float* emb_w = (const float*)d_in[2];
    const float* emb_b = (const float*)d_in[3];
    const float* pos   = (const float*)d_in[4];
    const float* Wq    = (const float*)d_in[5];
    const float* bq    = (const float*)d_in[6];
    const float* Wk    = (const float*)d_in[7];
    const float* bk    = (const float*)d_in[8];
    const float* Wv    = (const float*)d_in[9];
    const float* bv    = (const float*)d_in[10];
    const float* Wo    = (const float*)d_in[11];
    const float* bo    = (const float*)d_in[12];
    const float* g1    = (const float*)d_in[13];
    const float* be1   = (const float*)d_in[14];
    const float* W1    = (const float*)d_in[15];
    const float* b1    = (const float*)d_in[16];
    const float* W2    = (const float*)d_in[17];
    const float* b2    = (const float*)d_in[18];
    const float* g2    = (const float*)d_in[19];
    const float* be2   = (const float*)d_in[20];
    const float* fg    = (const float*)d_in[21];
    const float* fb    = (const float*)d_in[22];
    const float* hw    = (const float*)d_in[23];
    const float* hb    = (const float*)d_in[24];

    char* ws = (char*)d_ws;
    const long long SZ = 6304LL * 768 * 2;         // 9,682,944 B
    short* H  = (short*)(ws + 0 * SZ);
    short* Qb = (short*)(ws + 1 * SZ);
    short* Kb = (short*)(ws + 2 * SZ);
    short* Vb = (short*)(ws + 3 * SZ);
    short* AO = (short*)(ws + 4 * SZ);
    short* U  = (short*)(ws + 5 * SZ);
    short* T1 = (short*)(ws + 6 * SZ);             // patch-embed tmp / FFN hidden
    short* S  = (short*)(ws + 7 * SZ);             // 32*197*197*2 = 2,483,776 B
    short* hc = (short*)(ws + 7 * SZ + 2483776);   // 32*768*2

    const dim3 blk(256);
    const long long sQKV = 197LL * 768;  // 151296
    const long long sS   = 197LL * 197;  // 38809
    const float scale = 0.03608439182435161f;  // 768^-0.5

    // patch embed: T1[6272][768] = x[6272][256] @ emb_w + emb_b
    gemm_mfma<0, 0, 1, 1><<<dim3(98, 12, 1), blk, 0, stream>>>(
        x, 0, emb_w, 0, emb_b, nullptr, 0, T1, 0, 6272, 768, 256);
    assemble_k<<<dim3((32 * 197 * 768 + 255) / 256), blk, 0, stream>>>(T1, cls, pos, H);

    for (int l = 0; l < 12; ++l) {
        const long long wOff = (long long)l * 768 * 768;
        const long long vOff = (long long)l * 768;
        // QKV
        gemm_mfma<0, 0, 0, 1><<<dim3(99, 12, 1), blk, 0, stream>>>(
            H, 0, Wq + wOff, 0, bq + vOff, nullptr, 0, Qb, 0, 6304, 768, 768);
        gemm_mfma<0, 0, 0, 1><<<dim3(99, 12, 1), blk, 0, stream>>>(
            H, 0, Wk + wOff, 0, bk + vOff, nullptr, 0, Kb, 0, 6304, 768, 768);
        gemm_mfma<0, 0, 0, 1><<<dim3(99, 12, 1), blk, 0, stream>>>(
            H, 0, Wv + wOff, 0, bv + vOff, nullptr, 0, Vb, 0, 6304, 768, 768);
        // S = Q @ K^T  (batched; K-matrix is [n][k] naturally -> BT=1)
        gemm_mfma<0, 1, 0, 0><<<dim3(4, 4, 32), blk, 0, stream>>>(
            Qb, sQKV, Kb, sQKV, nullptr, nullptr, 0, S, sS, 197, 197, 768);
        softmax_k<<<dim3(32 * 197), blk, 0, stream>>>(S, scale);
        // AO = P @ V  (batched)
        gemm_mfma<0, 0, 0, 0><<<dim3(4, 12, 32), blk, 0, stream>>>(
            S, sS, Vb, sQKV, nullptr, nullptr, 0, AO, sQKV, 197, 768, 197);
        // U = AO @ Wo + bo + H ; H = LN(U)
        gemm_mfma<2, 0, 0, 1><<<dim3(99, 12, 1), blk, 0, stream>>>(
            AO, 0, Wo + wOff, 0, bo + vOff, H, 0, U, 0, 6304, 768, 768);
        ln_k<<<dim3(6304), blk, 0, stream>>>(U, 768, H, 768, g1 + vOff, be1 + vOff);
        // T1 = gelu(H @ W1 + b1) ; U = T1 @ W2 + b2 + H ; H = LN(U)
        gemm_mfma<1, 0, 0, 1><<<dim3(99, 12, 1), blk, 0, stream>>>(
            H, 0, W1 + wOff, 0, b1 + vOff, nullptr, 0, T1, 0, 6304, 768, 768);
        gemm_mfma<2, 0, 0, 1><<<dim3(99, 12, 1), blk, 0, stream>>>(
            T1, 0, W2 + wOff, 0, b2 + vOff, H, 0, U, 0, 6304, 768, 768);
        ln_k<<<dim3(6304), blk, 0, stream>>>(U, 768, H, 768, g2 + vOff, be2 + vOff);
    }

    // final LN on cls token + head
    ln_k<<<dim3(32), blk, 0, stream>>>(H, 197LL * 768, hc, 768, fg, fb);
    head_k<<<dim3(32), blk, 0, stream>>>(hc, hw, hb, (float*)d_out);
}

// Round 4
// 6911.115 us; speedup vs baseline: 1.2403x; 1.2403x over previous
//
#include <hip/hip_runtime.h>
#include <hip/hip_bf16.h>
#include <math.h>

typedef short short8 __attribute__((ext_vector_type(8)));
typedef float floatx4 __attribute__((ext_vector_type(4)));

#define DEV static __device__ __forceinline__

DEV float s2f(short v) {
    unsigned int u = ((unsigned int)(unsigned short)v) << 16;
    float f;
    __builtin_memcpy(&f, &u, 4);
    return f;
}
DEV short f2s(float f) {
    __hip_bfloat16 b = __float2bfloat16(f);   // RNE
    short s;
    __builtin_memcpy(&s, &b, 2);
    return s;
}

DEV void async_copy16(const void* g, void* l) {
    __builtin_amdgcn_global_load_lds(
        (const __attribute__((address_space(1))) void*)g,
        (__attribute__((address_space(3))) void*)l, 16, 0, 0);
}

// ---------------------------------------------------------------------------
// gemm128: C[M][N] = epi(A[M][K] @ Bt^T + bias [+ R])
// A bf16 [Mpad][lda] (rows tileM..tileM+127 must be readable)
// Bt bf16 [N][ldb] row-major = B transposed; N must be a multiple of 128.
// K multiple of 32. m97 structure: global_load_lds 16B staging, 128x128 tile,
// 4 waves, each wave a 64x64 quadrant of 4x4 16x16x32 MFMAs.
// EPI: 0 plain, 1 exact GELU, 2 add residual R (post-bias).
// ---------------------------------------------------------------------------
template<int EPI>
__global__ __launch_bounds__(256) void gemm128(
    const short* __restrict__ A, int lda,
    const short* __restrict__ Bt, int ldb,
    const float* __restrict__ bias,
    const short* __restrict__ R, int ldr,
    short* __restrict__ C, int ldc,
    int M, int N, int K)
{
    __shared__ short Asm[128 * 32];   // [m][k], no padding (global_load_lds)
    __shared__ short Bsm[128 * 32];   // [n][k]

    const int tid   = threadIdx.x;
    const int lane  = tid & 63;
    const int wave  = tid >> 6;
    const int tileM = blockIdx.x * 128;
    const int tileN = blockIdx.y * 128;
    const int wm    = (wave & 1) * 64;
    const int wn    = (wave >> 1) * 64;

    floatx4 acc[4][4];
    for (int mt = 0; mt < 4; ++mt)
        for (int nt = 0; nt < 4; ++nt)
            acc[mt][nt] = (floatx4){0.f, 0.f, 0.f, 0.f};

    for (int k0 = 0; k0 < K; k0 += 32) {
        // stage 128x32 A and B tiles: 512 chunks of 16B each, 2 per thread
#pragma unroll
        for (int i = 0; i < 2; ++i) {
            const int c   = i * 256 + tid;
            const int row = c >> 2;
            const int ko  = (c & 3) * 8;
            async_copy16(A  + (long long)(tileM + row) * lda + k0 + ko, &Asm[c * 8]);
            async_copy16(Bt + (long long)(tileN + row) * ldb + k0 + ko, &Bsm[c * 8]);
        }
        __syncthreads();   // drains vmcnt -> LDS data valid

        short8 af[4], bfr[4];
        const int ar = wm + (lane & 15);
        const int br = wn + (lane & 15);
        const int ko = (lane >> 4) * 8;
#pragma unroll
        for (int t = 0; t < 4; ++t) {
            af[t]  = *(const short8*)&Asm[(ar + t * 16) * 32 + ko];
            bfr[t] = *(const short8*)&Bsm[(br + t * 16) * 32 + ko];
        }
#pragma unroll
        for (int mt = 0; mt < 4; ++mt)
#pragma unroll
            for (int nt = 0; nt < 4; ++nt)
                acc[mt][nt] = __builtin_amdgcn_mfma_f32_16x16x32_bf16(
                    af[mt], bfr[nt], acc[mt][nt], 0, 0, 0);
        __syncthreads();
    }

    // epilogue: D row=(lane>>4)*4+r, col=lane&15
    const int col = lane & 15;
    const int rb  = (lane >> 4) * 4;
    for (int mt = 0; mt < 4; ++mt) {
        for (int nt = 0; nt < 4; ++nt) {
            const int gc = tileN + wn + nt * 16 + col;
            const float bv = bias ? bias[gc] : 0.0f;
            for (int r = 0; r < 4; ++r) {
                const int gr = tileM + wm + mt * 16 + rb + r;
                if (gr >= M) continue;
                float v = acc[mt][nt][r] + bv;
                if constexpr (EPI == 1) v = 0.5f * v * (1.0f + erff(v * 0.70710678118654752f));
                if constexpr (EPI == 2) v += s2f(R[(long long)gr * ldr + gc]);
                C[(long long)gr * ldc + gc] = f2s(v);
            }
        }
    }
}

// ---------------------------------------------------------------------------
// 64x64-tile bf16 GEMM (attention ops; small M/N, odd K). lda/ldb in elements.
//   BT=0: B is [K][ldb] k-major    BT=1: B is [N][ldb] n-major (QK^T)
// ---------------------------------------------------------------------------
template<int EPI, int BT>
__global__ __launch_bounds__(256) void gemm_mfma(
    const short* __restrict__ A, long long sA, int lda,
    const short* __restrict__ B, long long sB, int ldb,
    const float* __restrict__ bias,
    const short* __restrict__ R, long long sR,
    short* __restrict__ C, long long sC,
    int M, int N, int K)
{
    const int bz = blockIdx.z;
    A += (long long)bz * sA;
    B += (long long)bz * sB;
    C += (long long)bz * sC;
    if constexpr (EPI == 2) R += (long long)bz * sR;

    const int tileM = blockIdx.x * 64;
    const int tileN = blockIdx.y * 64;

    __shared__ short Al[64][40];
    __shared__ short Bl[64][40];

    const int tid  = threadIdx.x;
    const int lane = tid & 63;
    const int wave = tid >> 6;

    floatx4 acc[4] = { {0,0,0,0}, {0,0,0,0}, {0,0,0,0}, {0,0,0,0} };

    const int KT = (K + 31) / 32;
    const bool kvec = ((K & 7) == 0);

    for (int kt = 0; kt < KT; ++kt) {
        const int k0 = kt * 32;
        {   // A tile
            const int r  = tid >> 2;
            const int c0 = (tid & 3) * 8;
            const int gm = tileM + r;
            const int gk = k0 + c0;
            const short* Ap = A + (long long)gm * lda;
            short8 v;
            if (kvec && gm < M && gk + 8 <= K) {
                v = *(const short8*)(Ap + gk);
            } else {
                for (int j = 0; j < 8; ++j)
                    ((short*)&v)[j] = (gm < M && gk + j < K) ? Ap[gk + j] : (short)0;
            }
            *(short8*)&Al[r][c0] = v;
        }
        if constexpr (BT == 1) {
            const int r  = tid >> 2;
            const int c0 = (tid & 3) * 8;
            const int gn = tileN + r;
            const int gk = k0 + c0;
            const short* Bp = B + (long long)gn * ldb;
            short8 v;
            if (kvec && gn < N && gk + 8 <= K) {
                v = *(const short8*)(Bp + gk);
            } else {
                for (int j = 0; j < 8; ++j)
                    ((short*)&v)[j] = (gn < N && gk + j < K) ? Bp[gk + j] : (short)0;
            }
            *(short8*)&Bl[r][c0] = v;
        } else {
            const int n  = tid & 63;
            const int kg = tid >> 6;
            const int gn = tileN + n;
            short8 v;
            for (int j = 0; j < 8; ++j) {
                const int gk = k0 + kg * 8 + j;
                ((short*)&v)[j] = (gn < N && gk < K)
                    ? B[(long long)gk * ldb + gn] : (short)0;
            }
            *(short8*)&Bl[n][kg * 8] = v;
        }
        __syncthreads();

        const int mrow = wave * 16 + (lane & 15);
        const int koff = (lane >> 4) * 8;
        const short8 af = *(const short8*)&Al[mrow][koff];
        for (int ct = 0; ct < 4; ++ct) {
            const short8 bfrag = *(const short8*)&Bl[ct * 16 + (lane & 15)][koff];
            acc[ct] = __builtin_amdgcn_mfma_f32_16x16x32_bf16(af, bfrag, acc[ct], 0, 0, 0);
        }
        __syncthreads();
    }

    const int col0  = lane & 15;
    const int rbase = (lane >> 4) * 4;
    for (int ct = 0; ct < 4; ++ct) {
        const int gc = tileN + ct * 16 + col0;
        if (gc >= N) continue;
        const float bv = bias ? bias[gc] : 0.0f;
        for (int r = 0; r < 4; ++r) {
            const int gr = tileM + wave * 16 + rbase + r;
            if (gr >= M) continue;
            float v = acc[ct][r] + bv;
            if constexpr (EPI == 1) v = 0.5f * v * (1.0f + erff(v * 0.70710678118654752f));
            if constexpr (EPI == 2) v += s2f(R[(long long)gr * N + gc]);
            C[(long long)gr * N + gc] = f2s(v);
        }
    }
}

// ---------------------------------------------------------------------------
// Transpose-convert: out_bf16[z][n][k] = f2s(in_f32[z][k][n]). K,N mult of 32.
// block (32,8), grid (N/32, K/32, Z).
// ---------------------------------------------------------------------------
__global__ void tconv_k(const float* __restrict__ in, short* __restrict__ out,
                        int K, int N, long long inZ, long long outZ)
{
    __shared__ float t[32][33];
    in  += (long long)blockIdx.z * inZ;
    out += (long long)blockIdx.z * outZ;
    const int n0 = blockIdx.x * 32, k0 = blockIdx.y * 32;
    const int tx = threadIdx.x, ty = threadIdx.y;
#pragma unroll
    for (int i = 0; i < 4; ++i)
        t[ty + i * 8][tx] = in[(long long)(k0 + ty + i * 8) * N + n0 + tx];
    __syncthreads();
#pragma unroll
    for (int i = 0; i < 4; ++i)
        out[(long long)(n0 + ty + i * 8) * K + k0 + tx] = f2s(t[tx][ty + i * 8]);
}

// x fp32 -> bf16 flat
__global__ __launch_bounds__(256) void cvtx_k(const float* __restrict__ x,
                                              short* __restrict__ xb, int n)
{
    const int i = blockIdx.x * 256 + threadIdx.x;
    if (i < n) xb[i] = f2s(x[i]);
}

// concat per-layer q/k/v biases -> [12][2304] fp32
__global__ __launch_bounds__(256) void bqkv_k(
    const float* __restrict__ bq, const float* __restrict__ bk,
    const float* __restrict__ bv, float* __restrict__ out)
{
    const int i = blockIdx.x * 256 + threadIdx.x;
    if (i >= 12 * 2304) return;
    const int l = i / 2304, j = i % 2304;
    float v = (j < 768) ? bq[l * 768 + j]
            : (j < 1536) ? bk[l * 768 + j - 768]
                         : bv[l * 768 + j - 1536];
    out[i] = v;
}

// ---------------------------------------------------------------------------
// assemble: H[b][t][d] = (t==0 ? cls[d] : P[b*196+t-1][d]) + pos[t][d]
// ---------------------------------------------------------------------------
__global__ __launch_bounds__(256) void assemble_k(
    const short* __restrict__ P, const float* __restrict__ cls,
    const float* __restrict__ pos, short* __restrict__ H)
{
    const long long idx = (long long)blockIdx.x * 256 + threadIdx.x;
    if (idx >= 32LL * 197 * 768) return;
    const int d = (int)(idx % 768);
    const int t = (int)((idx / 768) % 197);
    const long long b = idx / (768LL * 197);
    float v = (t == 0) ? cls[d] : s2f(P[(b * 196 + t - 1) * 768 + d]);
    v += pos[t * 768 + d];
    H[idx] = f2s(v);
}

// ---------------------------------------------------------------------------
// softmax over last dim (197), in-place bf16, scale applied to logits
// ---------------------------------------------------------------------------
__global__ __launch_bounds__(256) void softmax_k(short* __restrict__ S, float scale)
{
    short* s = S + (long long)blockIdx.x * 197;
    const int tid = threadIdx.x;
    __shared__ float red[256];

    float x = 0.0f, v = -1e30f;
    if (tid < 197) { x = s2f(s[tid]) * scale; v = x; }
    red[tid] = v;
    __syncthreads();
    for (int st = 128; st > 0; st >>= 1) {
        if (tid < st) red[tid] = fmaxf(red[tid], red[tid + st]);
        __syncthreads();
    }
    const float mx = red[0];
    __syncthreads();
    const float e = (tid < 197) ? expf(x - mx) : 0.0f;
    red[tid] = e;
    __syncthreads();
    for (int st = 128; st > 0; st >>= 1) {
        if (tid < st) red[tid] += red[tid + st];
        __syncthreads();
    }
    const float inv = 1.0f / red[0];
    if (tid < 197) s[tid] = f2s(e * inv);
}

// ---------------------------------------------------------------------------
// LayerNorm over 768, one block per row
// ---------------------------------------------------------------------------
__global__ __launch_bounds__(256) void ln_k(
    const short* __restrict__ X, long long xs,
    short* __restrict__ Y, long long ys,
    const float* __restrict__ g, const float* __restrict__ be)
{
    const short* x = X + (long long)blockIdx.x * xs;
    short* y = Y + (long long)blockIdx.x * ys;
    const int tid = threadIdx.x;

    float v[3], s = 0.0f, sq = 0.0f;
    for (int i = 0; i < 3; ++i) {
        const float t = s2f(x[tid + 256 * i]);
        v[i] = t; s += t; sq += t * t;
    }
    __shared__ float r1[256], r2[256];
    r1[tid] = s; r2[tid] = sq;
    __syncthreads();
    for (int st = 128; st > 0; st >>= 1) {
        if (tid < st) { r1[tid] += r1[tid + st]; r2[tid] += r2[tid + st]; }
        __syncthreads();
    }
    const float m   = r1[0] * (1.0f / 768.0f);
    const float var = r2[0] * (1.0f / 768.0f) - m * m;
    const float rs  = rsqrtf(var + 1e-5f);
    for (int i = 0; i < 3; ++i) {
        const int d = tid + 256 * i;
        y[d] = f2s((v[i] - m) * rs * g[d] + be[d]);
    }
}

// ---------------------------------------------------------------------------
// head: out[b][c] = hc[b] . W[:,c] + hb[c], fp32 W/out. grid (4,32).
// Lane-consecutive c -> coalesced W reads.
// ---------------------------------------------------------------------------
__global__ __launch_bounds__(256) void head2_k(
    const short* __restrict__ hc, const float* __restrict__ W,
    const float* __restrict__ hb, float* __restrict__ out)
{
    const int b = blockIdx.y;
    const int c = blockIdx.x * 256 + threadIdx.x;
    __shared__ float h[768];
    for (int i = threadIdx.x; i < 768; i += 256) h[i] = s2f(hc[b * 768 + i]);
    __syncthreads();
    if (c >= 1000) return;
    float acc = hb[c];
    for (int k = 0; k < 768; ++k) acc += h[k] * W[k * 1000 + c];
    out[b * 1000 + c] = acc;
}

// ---------------------------------------------------------------------------
extern "C" void kernel_launch(void* const* d_in, const int* in_sizes, int n_in,
                              void* d_out, int out_size, void* d_ws, size_t ws_size,
                              hipStream_t stream)
{
    const float* x     = (const float*)d_in[0];
    const float* cls   = (const float*)d_in[1];
    const float* emb_w = (const float*)d_in[2];
    const float* emb_b = (const float*)d_in[3];
    const float* pos   = (const float*)d_in[4];
    const float* Wq    = (const float*)d_in[5];
    const float* bq    = (const float*)d_in[6];
    const float* Wk    = (const float*)d_in[7];
    const float* bk    = (const float*)d_in[8];
    const float* Wv    = (const float*)d_in[9];
    const float* bv    = (const float*)d_in[10];
    const float* Wo    = (const float*)d_in[11];
    const float* bo    = (const float*)d_in[12];
    const float* g1    = (const float*)d_in[13];
    const float* be1   = (const float*)d_in[14];
    const float* W1    = (const float*)d_in[15];
    const float* b1    = (const float*)d_in[16];
    const float* W2    = (const float*)d_in[17];
    const float* b2    = (const float*)d_in[18];
    const float* g2    = (const float*)d_in[19];
    const float* be2   = (const float*)d_in[20];
    const float* fg    = (const float*)d_in[21];
    const float* fb    = (const float*)d_in[22];
    const float* hw    = (const float*)d_in[23];
    const float* hb    = (const float*)d_in[24];

    char* ws = (char*)d_ws;
    long long o = 0;
    short* WtQKV = (short*)(ws + o); o += 12LL * 2304 * 768 * 2;   // 42,467,328
    short* WtO   = (short*)(ws + o); o += 12LL * 768 * 768 * 2;    // 14,155,776
    short* Wt1   = (short*)(ws + o); o += 12LL * 768 * 768 * 2;
    short* Wt2   = (short*)(ws + o); o += 12LL * 768 * 768 * 2;
    short* embT  = (short*)(ws + o); o += 768LL * 256 * 2;
    short* xb    = (short*)(ws + o); o += 6400LL * 256 * 2;
    short* H     = (short*)(ws + o); o += 6400LL * 768 * 2;
    short* QKVb  = (short*)(ws + o); o += 6400LL * 2304 * 2;
    short* AO    = (short*)(ws + o); o += 6400LL * 768 * 2;
    short* T1    = (short*)(ws + o); o += 6400LL * 768 * 2;
    short* S     = (short*)(ws + o); o += 32LL * 197 * 197 * 2 + 14; o &= ~15LL;
    short* hc    = (short*)(ws + o); o += 32LL * 768 * 2;
    float* bqkv  = (float*)(ws + o); o += 12LL * 2304 * 4;

    const dim3 blk(256);
    const dim3 tblk(32, 8);
    const float scale = 0.03608439182435161f;  // 768^-0.5
    const long long sQ = 197LL * 2304;
    const long long sS = 197LL * 197;

    // ---- prep: transpose-convert weights, convert x, concat qkv bias ----
    tconv_k<<<dim3(24, 8, 1),  tblk, 0, stream>>>(emb_w, embT, 256, 768, 0, 0);
    tconv_k<<<dim3(24, 24, 12), tblk, 0, stream>>>(Wq, WtQKV,               768, 768, 589824, 2304LL * 768);
    tconv_k<<<dim3(24, 24, 12), tblk, 0, stream>>>(Wk, WtQKV +  768 * 768,  768, 768, 589824, 2304LL * 768);
    tconv_k<<<dim3(24, 24, 12), tblk, 0, stream>>>(Wv, WtQKV + 1536 * 768,  768, 768, 589824, 2304LL * 768);
    tconv_k<<<dim3(24, 24, 12), tblk, 0, stream>>>(Wo, WtO, 768, 768, 589824, 589824);
    tconv_k<<<dim3(24, 24, 12), tblk, 0, stream>>>(W1, Wt1, 768, 768, 589824, 589824);
    tconv_k<<<dim3(24, 24, 12), tblk, 0, stream>>>(W2, Wt2, 768, 768, 589824, 589824);
    cvtx_k<<<dim3(6272), blk, 0, stream>>>(x, xb, 6272 * 256);
    bqkv_k<<<dim3(108), blk, 0, stream>>>(bq, bk, bv, bqkv);

    // ---- patch embed + assemble ----
    gemm128<0><<<dim3(49, 6), blk, 0, stream>>>(
        xb, 256, embT, 256, emb_b, nullptr, 0, T1, 768, 6272, 768, 256);
    assemble_k<<<dim3((32 * 197 * 768 + 255) / 256), blk, 0, stream>>>(T1, cls, pos, H);

    for (int l = 0; l < 12; ++l) {
        const long long w1o = (long long)l * 589824;
        const long long vo  = (long long)l * 768;
        // fused QKV: [6304][2304]
        gemm128<0><<<dim3(50, 18), blk, 0, stream>>>(
            H, 768, WtQKV + (long long)l * 2304 * 768, 768, bqkv + l * 2304,
            nullptr, 0, QKVb, 2304, 6304, 2304, 768);
        // S = Q @ K^T (batched)
        gemm_mfma<0, 1><<<dim3(4, 4, 32), blk, 0, stream>>>(
            QKVb, sQ, 2304, QKVb + 768, sQ, 2304, nullptr, nullptr, 0,
            S, sS, 197, 197, 768);
        softmax_k<<<dim3(32 * 197), blk, 0, stream>>>(S, scale);
        // AO = P @ V (batched)
        gemm_mfma<0, 0><<<dim3(4, 12, 32), blk, 0, stream>>>(
            S, sS, 197, QKVb + 1536, sQ, 2304, nullptr, nullptr, 0,
            AO, 197LL * 768, 197, 768, 197);
        // T1 = AO @ Wo + bo + H ; H = LN(T1)
        gemm128<2><<<dim3(50, 6), blk, 0, stream>>>(
            AO, 768, WtO + w1o, 768, bo + vo, H, 768, T1, 768, 6304, 768, 768);
        ln_k<<<dim3(6304), blk, 0, stream>>>(T1, 768, H, 768, g1 + vo, be1 + vo);
        // T1 = gelu(H @ W1 + b1) ; AO = T1 @ W2 + b2 + H ; H = LN(AO)
        gemm128<1><<<dim3(50, 6), blk, 0, stream>>>(
            H, 768, Wt1 + w1o, 768, b1 + vo, nullptr, 0, T1, 768, 6304, 768, 768);
        gemm128<2><<<dim3(50, 6), blk, 0, stream>>>(
            T1, 768, Wt2 + w1o, 768, b2 + vo, H, 768, AO, 768, 6304, 768, 768);
        ln_k<<<dim3(6304), blk, 0, stream>>>(AO, 768, H, 768, g2 + vo, be2 + vo);
    }

    // final LN on cls token + head
    ln_k<<<dim3(32), blk, 0, stream>>>(H, 197LL * 768, hc, 768, fg, fb);
    head2_k<<<dim3(4, 32), blk, 0, stream>>>(hc, hw, hb, (float*)d_out);
}

// Round 5
// 2839.538 us; speedup vs baseline: 3.0187x; 2.4339x over previous
//
#include <hip/hip_runtime.h>
#include <hip/hip_bf16.h>
#include <math.h>

typedef short short8 __attribute__((ext_vector_type(8)));
typedef float floatx4 __attribute__((ext_vector_type(4)));

#define DEV static __device__ __forceinline__

DEV float s2f(short v) {
    unsigned int u = ((unsigned int)(unsigned short)v) << 16;
    float f;
    __builtin_memcpy(&f, &u, 4);
    return f;
}
DEV short f2s(float f) {
    __hip_bfloat16 b = __float2bfloat16(f);   // RNE
    short s;
    __builtin_memcpy(&s, &b, 2);
    return s;
}

DEV void async_copy16(const void* g, void* l) {
    __builtin_amdgcn_global_load_lds(
        (const __attribute__((address_space(1))) void*)g,
        (__attribute__((address_space(3))) void*)l, 16, 0, 0);
}

// ---------------------------------------------------------------------------
// gemm128 v2: C[M][N] = epi(A[M][K] @ Bt^T + bias [+ R])
// A bf16 [.][lda] rows tileM..+127 readable; Bt bf16 [N][ldb]; N mult 128;
// K mult 64. BK=64 as two m97-style 32-k panels; wide LDS-staged epilogue.
// EPI: 0 plain, 1 exact GELU, 2 residual add.
// ---------------------------------------------------------------------------
template<int EPI>
__global__ __launch_bounds__(256) void gemm128(
    const short* __restrict__ A, int lda,
    const short* __restrict__ Bt, int ldb,
    const float* __restrict__ bias,
    const short* __restrict__ R, int ldr,
    short* __restrict__ C, int ldc,
    int M, int N, int K)
{
    __shared__ short smem[4 * 4096];   // panels A0,A1,B0,B1 (32 KB); reused by epilogue

    const int tid   = threadIdx.x;
    const int lane  = tid & 63;
    const int wave  = tid >> 6;
    const int tileM = blockIdx.x * 128;
    const int tileN = blockIdx.y * 128;
    const int wm    = (wave & 1) * 64;
    const int wn    = (wave >> 1) * 64;

    floatx4 acc[4][4];
#pragma unroll
    for (int mt = 0; mt < 4; ++mt)
#pragma unroll
        for (int nt = 0; nt < 4; ++nt)
            acc[mt][nt] = (floatx4){0.f, 0.f, 0.f, 0.f};

    for (int k0 = 0; k0 < K; k0 += 64) {
        // stage 4 panels of 128x32 bf16; each: 512 16-B chunks, m97 pattern
#pragma unroll
        for (int h = 0; h < 2; ++h) {
#pragma unroll
            for (int i = 0; i < 2; ++i) {
                const int c   = i * 256 + tid;
                const int row = c >> 2;
                const int ko  = (c & 3) * 8;
                async_copy16(A  + (long long)(tileM + row) * lda + k0 + h * 32 + ko,
                             &smem[h * 4096 + c * 8]);
                async_copy16(Bt + (long long)(tileN + row) * ldb + k0 + h * 32 + ko,
                             &smem[8192 + h * 4096 + c * 8]);
            }
        }
        __syncthreads();

        const int fr = lane & 15;
        const int ko = (lane >> 4) * 8;
#pragma unroll
        for (int h = 0; h < 2; ++h) {
            const short* pA = &smem[h * 4096];
            const short* pB = &smem[8192 + h * 4096];
            short8 af[4], bf[4];
#pragma unroll
            for (int t = 0; t < 4; ++t) {
                af[t] = *(const short8*)&pA[(wm + fr + t * 16) * 32 + ko];
                bf[t] = *(const short8*)&pB[(wn + fr + t * 16) * 32 + ko];
            }
#pragma unroll
            for (int mt = 0; mt < 4; ++mt)
#pragma unroll
                for (int nt = 0; nt < 4; ++nt)
                    acc[mt][nt] = __builtin_amdgcn_mfma_f32_16x16x32_bf16(
                        af[mt], bf[nt], acc[mt][nt], 0, 0, 0);
        }
        __syncthreads();
    }

    // ---- epilogue: wave-private fp32 LDS stage -> coalesced short8 stores ----
    float* eps = (float*)smem + wave * (16 * 68);   // 16 rows x 68 (padded)
    const int col = lane & 15;
    const int rb  = (lane >> 4) * 4;
    for (int mt = 0; mt < 4; ++mt) {
        const int gr0 = tileM + wm + mt * 16;
        const int gc0 = tileN + wn;
#pragma unroll
        for (int nt = 0; nt < 4; ++nt) {
            const float bv = bias ? bias[gc0 + nt * 16 + col] : 0.0f;
#pragma unroll
            for (int r = 0; r < 4; ++r) {
                float v = acc[mt][nt][r] + bv;
                if constexpr (EPI == 1) v = 0.5f * v * (1.0f + erff(v * 0.70710678118654752f));
                eps[(rb + r) * 68 + nt * 16 + col] = v;
            }
        }
        // wave-private region: DS ops are in-order per wave; no barrier needed
#pragma unroll
        for (int j = 0; j < 2; ++j) {
            const int r  = (lane >> 3) + 8 * j;
            const int cb = (lane & 7) * 8;
            const floatx4 f0 = *(const floatx4*)&eps[r * 68 + cb];
            const floatx4 f1 = *(const floatx4*)&eps[r * 68 + cb + 4];
            const int gr = gr0 + r;
            if (gr >= M) continue;
            short8 o;
            if constexpr (EPI == 2) {
                const short8 rr = *(const short8*)&R[(long long)gr * ldr + gc0 + cb];
#pragma unroll
                for (int i = 0; i < 4; ++i) {
                    o[i]     = f2s(f0[i] + s2f(rr[i]));
                    o[4 + i] = f2s(f1[i] + s2f(rr[4 + i]));
                }
            } else {
#pragma unroll
                for (int i = 0; i < 4; ++i) {
                    o[i]     = f2s(f0[i]);
                    o[4 + i] = f2s(f1[i]);
                }
            }
            *(short8*)&C[(long long)gr * ldc + gc0 + cb] = o;
        }
    }
}

// ---------------------------------------------------------------------------
// 64x64-tile bf16 GEMM (attention ops; small M/N, odd K). lda/ldb in elements.
//   BT=0: B is [K][ldb] k-major    BT=1: B is [N][ldb] n-major (QK^T)
// ---------------------------------------------------------------------------
template<int EPI, int BT>
__global__ __launch_bounds__(256) void gemm_mfma(
    const short* __restrict__ A, long long sA, int lda,
    const short* __restrict__ B, long long sB, int ldb,
    const float* __restrict__ bias,
    const short* __restrict__ R, long long sR,
    short* __restrict__ C, long long sC,
    int M, int N, int K)
{
    const int bz = blockIdx.z;
    A += (long long)bz * sA;
    B += (long long)bz * sB;
    C += (long long)bz * sC;
    if constexpr (EPI == 2) R += (long long)bz * sR;

    const int tileM = blockIdx.x * 64;
    const int tileN = blockIdx.y * 64;

    __shared__ short Al[64][40];
    __shared__ short Bl[64][40];

    const int tid  = threadIdx.x;
    const int lane = tid & 63;
    const int wave = tid >> 6;

    floatx4 acc[4] = { {0,0,0,0}, {0,0,0,0}, {0,0,0,0}, {0,0,0,0} };

    const int KT = (K + 31) / 32;
    const bool kvec = ((K & 7) == 0);

    for (int kt = 0; kt < KT; ++kt) {
        const int k0 = kt * 32;
        {   // A tile
            const int r  = tid >> 2;
            const int c0 = (tid & 3) * 8;
            const int gm = tileM + r;
            const int gk = k0 + c0;
            const short* Ap = A + (long long)gm * lda;
            short8 v;
            if (kvec && gm < M && gk + 8 <= K) {
                v = *(const short8*)(Ap + gk);
            } else {
                for (int j = 0; j < 8; ++j)
                    ((short*)&v)[j] = (gm < M && gk + j < K) ? Ap[gk + j] : (short)0;
            }
            *(short8*)&Al[r][c0] = v;
        }
        if constexpr (BT == 1) {
            const int r  = tid >> 2;
            const int c0 = (tid & 3) * 8;
            const int gn = tileN + r;
            const int gk = k0 + c0;
            const short* Bp = B + (long long)gn * ldb;
            short8 v;
            if (kvec && gn < N && gk + 8 <= K) {
                v = *(const short8*)(Bp + gk);
            } else {
                for (int j = 0; j < 8; ++j)
                    ((short*)&v)[j] = (gn < N && gk + j < K) ? Bp[gk + j] : (short)0;
            }
            *(short8*)&Bl[r][c0] = v;
        } else {
            const int n  = tid & 63;
            const int kg = tid >> 6;
            const int gn = tileN + n;
            short8 v;
            for (int j = 0; j < 8; ++j) {
                const int gk = k0 + kg * 8 + j;
                ((short*)&v)[j] = (gn < N && gk < K)
                    ? B[(long long)gk * ldb + gn] : (short)0;
            }
            *(short8*)&Bl[n][kg * 8] = v;
        }
        __syncthreads();

        const int mrow = wave * 16 + (lane & 15);
        const int koff = (lane >> 4) * 8;
        const short8 af = *(const short8*)&Al[mrow][koff];
        for (int ct = 0; ct < 4; ++ct) {
            const short8 bfrag = *(const short8*)&Bl[ct * 16 + (lane & 15)][koff];
            acc[ct] = __builtin_amdgcn_mfma_f32_16x16x32_bf16(af, bfrag, acc[ct], 0, 0, 0);
        }
        __syncthreads();
    }

    const int col0  = lane & 15;
    const int rbase = (lane >> 4) * 4;
    for (int ct = 0; ct < 4; ++ct) {
        const int gc = tileN + ct * 16 + col0;
        if (gc >= N) continue;
        const float bv = bias ? bias[gc] : 0.0f;
        for (int r = 0; r < 4; ++r) {
            const int gr = tileM + wave * 16 + rbase + r;
            if (gr >= M) continue;
            float v = acc[ct][r] + bv;
            if constexpr (EPI == 1) v = 0.5f * v * (1.0f + erff(v * 0.70710678118654752f));
            if constexpr (EPI == 2) v += s2f(R[(long long)gr * N + gc]);
            C[(long long)gr * N + gc] = f2s(v);
        }
    }
}

// ---------------------------------------------------------------------------
// Transpose-convert: out_bf16[z][n][k] = f2s(in_f32[z][k][n]). K,N mult of 32.
// block (32,8), grid (N/32, K/32, Z).
// ---------------------------------------------------------------------------
__global__ void tconv_k(const float* __restrict__ in, short* __restrict__ out,
                        int K, int N, long long inZ, long long outZ)
{
    __shared__ float t[32][33];
    in  += (long long)blockIdx.z * inZ;
    out += (long long)blockIdx.z * outZ;
    const int n0 = blockIdx.x * 32, k0 = blockIdx.y * 32;
    const int tx = threadIdx.x, ty = threadIdx.y;
#pragma unroll
    for (int i = 0; i < 4; ++i)
        t[ty + i * 8][tx] = in[(long long)(k0 + ty + i * 8) * N + n0 + tx];
    __syncthreads();
#pragma unroll
    for (int i = 0; i < 4; ++i)
        out[(long long)(n0 + ty + i * 8) * K + k0 + tx] = f2s(t[tx][ty + i * 8]);
}

// x fp32 -> bf16 flat
__global__ __launch_bounds__(256) void cvtx_k(const float* __restrict__ x,
                                              short* __restrict__ xb, int n)
{
    const int i = blockIdx.x * 256 + threadIdx.x;
    if (i < n) xb[i] = f2s(x[i]);
}

// concat per-layer q/k/v biases -> [12][2304] fp32
__global__ __launch_bounds__(256) void bqkv_k(
    const float* __restrict__ bq, const float* __restrict__ bk,
    const float* __restrict__ bv, float* __restrict__ out)
{
    const int i = blockIdx.x * 256 + threadIdx.x;
    if (i >= 12 * 2304) return;
    const int l = i / 2304, j = i % 2304;
    float v = (j < 768) ? bq[l * 768 + j]
            : (j < 1536) ? bk[l * 768 + j - 768]
                         : bv[l * 768 + j - 1536];
    out[i] = v;
}

// ---------------------------------------------------------------------------
// assemble: H[b][t][d] = (t==0 ? cls[d] : P[b*196+t-1][d]) + pos[t][d]
// ---------------------------------------------------------------------------
__global__ __launch_bounds__(256) void assemble_k(
    const short* __restrict__ P, const float* __restrict__ cls,
    const float* __restrict__ pos, short* __restrict__ H)
{
    const long long idx = (long long)blockIdx.x * 256 + threadIdx.x;
    if (idx >= 32LL * 197 * 768) return;
    const int d = (int)(idx % 768);
    const int t = (int)((idx / 768) % 197);
    const long long b = idx / (768LL * 197);
    float v = (t == 0) ? cls[d] : s2f(P[(b * 196 + t - 1) * 768 + d]);
    v += pos[t * 768 + d];
    H[idx] = f2s(v);
}

// ---------------------------------------------------------------------------
// softmax over last dim (197), in-place bf16, scale applied to logits
// ---------------------------------------------------------------------------
__global__ __launch_bounds__(256) void softmax_k(short* __restrict__ S, float scale)
{
    short* s = S + (long long)blockIdx.x * 197;
    const int tid = threadIdx.x;
    __shared__ float red[256];

    float x = 0.0f, v = -1e30f;
    if (tid < 197) { x = s2f(s[tid]) * scale; v = x; }
    red[tid] = v;
    __syncthreads();
    for (int st = 128; st > 0; st >>= 1) {
        if (tid < st) red[tid] = fmaxf(red[tid], red[tid + st]);
        __syncthreads();
    }
    const float mx = red[0];
    __syncthreads();
    const float e = (tid < 197) ? expf(x - mx) : 0.0f;
    red[tid] = e;
    __syncthreads();
    for (int st = 128; st > 0; st >>= 1) {
        if (tid < st) red[tid] += red[tid + st];
        __syncthreads();
    }
    const float inv = 1.0f / red[0];
    if (tid < 197) s[tid] = f2s(e * inv);
}

// ---------------------------------------------------------------------------
// LayerNorm over 768, one block per row
// ---------------------------------------------------------------------------
__global__ __launch_bounds__(256) void ln_k(
    const short* __restrict__ X, long long xs,
    short* __restrict__ Y, long long ys,
    const float* __restrict__ g, const float* __restrict__ be)
{
    const short* x = X + (long long)blockIdx.x * xs;
    short* y = Y + (long long)blockIdx.x * ys;
    const int tid = threadIdx.x;

    float v[3], s = 0.0f, sq = 0.0f;
    for (int i = 0; i < 3; ++i) {
        const float t = s2f(x[tid + 256 * i]);
        v[i] = t; s += t; sq += t * t;
    }
    __shared__ float r1[256], r2[256];
    r1[tid] = s; r2[tid] = sq;
    __syncthreads();
    for (int st = 128; st > 0; st >>= 1) {
        if (tid < st) { r1[tid] += r1[tid + st]; r2[tid] += r2[tid + st]; }
        __syncthreads();
    }
    const float m   = r1[0] * (1.0f / 768.0f);
    const float var = r2[0] * (1.0f / 768.0f) - m * m;
    const float rs  = rsqrtf(var + 1e-5f);
    for (int i = 0; i < 3; ++i) {
        const int d = tid + 256 * i;
        y[d] = f2s((v[i] - m) * rs * g[d] + be[d]);
    }
}

// ---------------------------------------------------------------------------
// head: out[b][c] = hc[b] . W[:,c] + hb[c], fp32 W/out. grid (4,32).
// ---------------------------------------------------------------------------
__global__ __launch_bounds__(256) void head2_k(
    const short* __restrict__ hc, const float* __restrict__ W,
    const float* __restrict__ hb, float* __restrict__ out)
{
    const int b = blockIdx.y;
    const int c = blockIdx.x * 256 + threadIdx.x;
    __shared__ float h[768];
    for (int i = threadIdx.x; i < 768; i += 256) h[i] = s2f(hc[b * 768 + i]);
    __syncthreads();
    if (c >= 1000) return;
    float acc = hb[c];
    for (int k = 0; k < 768; ++k) acc += h[k] * W[k * 1000 + c];
    out[b * 1000 + c] = acc;
}

// ---------------------------------------------------------------------------
extern "C" void kernel_launch(void* const* d_in, const int* in_sizes, int n_in,
                              void* d_out, int out_size, void* d_ws, size_t ws_size,
                              hipStream_t stream)
{
    const float* x     = (const float*)d_in[0];
    const float* cls   = (const float*)d_in[1];
    const float* emb_w = (const float*)d_in[2];
    const float* emb_b = (const float*)d_in[3];
    const float* pos   = (const float*)d_in[4];
    const float* Wq    = (const float*)d_in[5];
    const float* bq    = (const float*)d_in[6];
    const float* Wk    = (const float*)d_in[7];
    const float* bk    = (const float*)d_in[8];
    const float* Wv    = (const float*)d_in[9];
    const float* bv    = (const float*)d_in[10];
    const float* Wo    = (const float*)d_in[11];
    const float* bo    = (const float*)d_in[12];
    const float* g1    = (const float*)d_in[13];
    const float* be1   = (const float*)d_in[14];
    const float* W1    = (const float*)d_in[15];
    const float* b1    = (const float*)d_in[16];
    const float* W2    = (const float*)d_in[17];
    const float* b2    = (const float*)d_in[18];
    const float* g2    = (const float*)d_in[19];
    const float* be2   = (const float*)d_in[20];
    const float* fg    = (const float*)d_in[21];
    const float* fb    = (const float*)d_in[22];
    const float* hw    = (const float*)d_in[23];
    const float* hb    = (const float*)d_in[24];

    char* ws = (char*)d_ws;
    long long o = 0;
    short* WtQKV = (short*)(ws + o); o += 12LL * 2304 * 768 * 2;
    short* WtO   = (short*)(ws + o); o += 12LL * 768 * 768 * 2;
    short* Wt1   = (short*)(ws + o); o += 12LL * 768 * 768 * 2;
    short* Wt2   = (short*)(ws + o); o += 12LL * 768 * 768 * 2;
    short* embT  = (short*)(ws + o); o += 768LL * 256 * 2;
    short* xb    = (short*)(ws + o); o += 6400LL * 256 * 2;
    short* H     = (short*)(ws + o); o += 6400LL * 768 * 2;
    short* QKVb  = (short*)(ws + o); o += 6400LL * 2304 * 2;
    short* AO    = (short*)(ws + o); o += 6400LL * 768 * 2;
    short* T1    = (short*)(ws + o); o += 6400LL * 768 * 2;
    short* S     = (short*)(ws + o); o += 32LL * 197 * 197 * 2 + 14; o &= ~15LL;
    short* hc    = (short*)(ws + o); o += 32LL * 768 * 2;
    float* bqkv  = (float*)(ws + o); o += 12LL * 2304 * 4;

    const dim3 blk(256);
    const dim3 tblk(32, 8);
    const float scale = 0.03608439182435161f;  // 768^-0.5
    const long long sQ = 197LL * 2304;
    const long long sS = 197LL * 197;

    // ---- prep: transpose-convert weights, convert x, concat qkv bias ----
    tconv_k<<<dim3(24, 8, 1),  tblk, 0, stream>>>(emb_w, embT, 256, 768, 0, 0);
    tconv_k<<<dim3(24, 24, 12), tblk, 0, stream>>>(Wq, WtQKV,               768, 768, 589824, 2304LL * 768);
    tconv_k<<<dim3(24, 24, 12), tblk, 0, stream>>>(Wk, WtQKV +  768 * 768,  768, 768, 589824, 2304LL * 768);
    tconv_k<<<dim3(24, 24, 12), tblk, 0, stream>>>(Wv, WtQKV + 1536 * 768,  768, 768, 589824, 2304LL * 768);
    tconv_k<<<dim3(24, 24, 12), tblk, 0, stream>>>(Wo, WtO, 768, 768, 589824, 589824);
    tconv_k<<<dim3(24, 24, 12), tblk, 0, stream>>>(W1, Wt1, 768, 768, 589824, 589824);
    tconv_k<<<dim3(24, 24, 12), tblk, 0, stream>>>(W2, Wt2, 768, 768, 589824, 589824);
    cvtx_k<<<dim3(6272), blk, 0, stream>>>(x, xb, 6272 * 256);
    bqkv_k<<<dim3(108), blk, 0, stream>>>(bq, bk, bv, bqkv);

    // ---- patch embed + assemble ----
    gemm128<0><<<dim3(49, 6), blk, 0, stream>>>(
        xb, 256, embT, 256, emb_b, nullptr, 0, T1, 768, 6272, 768, 256);
    assemble_k<<<dim3((32 * 197 * 768 + 255) / 256), blk, 0, stream>>>(T1, cls, pos, H);

    for (int l = 0; l < 12; ++l) {
        const long long w1o = (long long)l * 589824;
        const long long vo  = (long long)l * 768;
        // fused QKV: [6304][2304]
        gemm128<0><<<dim3(50, 18), blk, 0, stream>>>(
            H, 768, WtQKV + (long long)l * 2304 * 768, 768, bqkv + l * 2304,
            nullptr, 0, QKVb, 2304, 6304, 2304, 768);
        // S = Q @ K^T (batched)
        gemm_mfma<0, 1><<<dim3(4, 4, 32), blk, 0, stream>>>(
            QKVb, sQ, 2304, QKVb + 768, sQ, 2304, nullptr, nullptr, 0,
            S, sS, 197, 197, 768);
        softmax_k<<<dim3(32 * 197), blk, 0, stream>>>(S, scale);
        // AO = P @ V (batched)
        gemm_mfma<0, 0><<<dim3(4, 12, 32), blk, 0, stream>>>(
            S, sS, 197, QKVb + 1536, sQ, 2304, nullptr, nullptr, 0,
            AO, 197LL * 768, 197, 768, 197);
        // T1 = AO @ Wo + bo + H ; H = LN(T1)
        gemm128<2><<<dim3(50, 6), blk, 0, stream>>>(
            AO, 768, WtO + w1o, 768, bo + vo, H, 768, T1, 768, 6304, 768, 768);
        ln_k<<<dim3(6304), blk, 0, stream>>>(T1, 768, H, 768, g1 + vo, be1 + vo);
        // T1 = gelu(H @ W1 + b1) ; AO = T1 @ W2 + b2 + H ; H = LN(AO)
        gemm128<1><<<dim3(50, 6), blk, 0, stream>>>(
            H, 768, Wt1 + w1o, 768, b1 + vo, nullptr, 0, T1, 768, 6304, 768, 768);
        gemm128<2><<<dim3(50, 6), blk, 0, stream>>>(
            T1, 768, Wt2 + w1o, 768, b2 + vo, H, 768, AO, 768, 6304, 768, 768);
        ln_k<<<dim3(6304), blk, 0, stream>>>(AO, 768, H, 768, g2 + vo, be2 + vo);
    }

    // final LN on cls token + head
    ln_k<<<dim3(32), blk, 0, stream>>>(H, 197LL * 768, hc, 768, fg, fb);
    head2_k<<<dim3(4, 32), blk, 0, stream>>>(hc, hw, hb, (float*)d_out);
}

// Round 6
// 2593.492 us; speedup vs baseline: 3.3050x; 1.0949x over previous
//
#include <hip/hip_runtime.h>
#include <hip/hip_bf16.h>
#include <math.h>

typedef short short8 __attribute__((ext_vector_type(8)));
typedef float floatx4 __attribute__((ext_vector_type(4)));

#define DEV static __device__ __forceinline__

DEV float s2f(short v) {
    unsigned int u = ((unsigned int)(unsigned short)v) << 16;
    float f;
    __builtin_memcpy(&f, &u, 4);
    return f;
}
DEV short f2s(float f) {
    __hip_bfloat16 b = __float2bfloat16(f);   // RNE
    short s;
    __builtin_memcpy(&s, &b, 2);
    return s;
}

DEV void async_copy16(const void* g, void* l) {
    __builtin_amdgcn_global_load_lds(
        (const __attribute__((address_space(1))) void*)g,
        (__attribute__((address_space(3))) void*)l, 16, 0, 0);
}

// ---------------------------------------------------------------------------
// gemm128 v3: C[M][N] = epi(A[M][K] @ Bt^T [+ bias] [+ R])   (z-batched)
// A bf16 rows tileM..+127 readable; Bt bf16 [N][ldb]; N mult 128; K mult 64.
// BK=64 as two m97-style 32-k panels; wide LDS-staged epilogue (short8 stores).
// EPI: 0 plain(+col bias), 1 exact GELU(+col bias), 2 +col bias +residual R,
//      3 +ROW bias (bias indexed by output row; used for V^T).
// ---------------------------------------------------------------------------
template<int EPI>
__global__ __launch_bounds__(256) void gemm128(
    const short* __restrict__ A, long long zA, int lda,
    const short* __restrict__ Bt, long long zB, int ldb,
    const float* __restrict__ bias,
    const short* __restrict__ R, int ldr,
    short* __restrict__ C, long long zC, int ldc,
    int M, int N, int K)
{
    __shared__ short smem[4 * 4096];   // panels A0,A1,B0,B1 (32 KB); reused by epilogue

    A  += (long long)blockIdx.z * zA;
    Bt += (long long)blockIdx.z * zB;
    C  += (long long)blockIdx.z * zC;

    const int tid   = threadIdx.x;
    const int lane  = tid & 63;
    const int wave  = tid >> 6;
    const int tileM = blockIdx.x * 128;
    const int tileN = blockIdx.y * 128;
    const int wm    = (wave & 1) * 64;
    const int wn    = (wave >> 1) * 64;

    floatx4 acc[4][4];
#pragma unroll
    for (int mt = 0; mt < 4; ++mt)
#pragma unroll
        for (int nt = 0; nt < 4; ++nt)
            acc[mt][nt] = (floatx4){0.f, 0.f, 0.f, 0.f};

    for (int k0 = 0; k0 < K; k0 += 64) {
#pragma unroll
        for (int h = 0; h < 2; ++h) {
#pragma unroll
            for (int i = 0; i < 2; ++i) {
                const int c   = i * 256 + tid;
                const int row = c >> 2;
                const int ko  = (c & 3) * 8;
                async_copy16(A  + (long long)(tileM + row) * lda + k0 + h * 32 + ko,
                             &smem[h * 4096 + c * 8]);
                async_copy16(Bt + (long long)(tileN + row) * ldb + k0 + h * 32 + ko,
                             &smem[8192 + h * 4096 + c * 8]);
            }
        }
        __syncthreads();

        const int fr = lane & 15;
        const int ko = (lane >> 4) * 8;
#pragma unroll
        for (int h = 0; h < 2; ++h) {
            const short* pA = &smem[h * 4096];
            const short* pB = &smem[8192 + h * 4096];
            short8 af[4], bf[4];
#pragma unroll
            for (int t = 0; t < 4; ++t) {
                af[t] = *(const short8*)&pA[(wm + fr + t * 16) * 32 + ko];
                bf[t] = *(const short8*)&pB[(wn + fr + t * 16) * 32 + ko];
            }
#pragma unroll
            for (int mt = 0; mt < 4; ++mt)
#pragma unroll
                for (int nt = 0; nt < 4; ++nt)
                    acc[mt][nt] = __builtin_amdgcn_mfma_f32_16x16x32_bf16(
                        af[mt], bf[nt], acc[mt][nt], 0, 0, 0);
        }
        __syncthreads();
    }

    // ---- epilogue: wave-private fp32 LDS stage -> coalesced short8 stores ----
    float* eps = (float*)smem + wave * (16 * 68);
    const int col = lane & 15;
    const int rb  = (lane >> 4) * 4;
    for (int mt = 0; mt < 4; ++mt) {
        const int gr0 = tileM + wm + mt * 16;
        const int gc0 = tileN + wn;
#pragma unroll
        for (int nt = 0; nt < 4; ++nt) {
            float bv = 0.0f;
            if constexpr (EPI != 3) { if (bias) bv = bias[gc0 + nt * 16 + col]; }
#pragma unroll
            for (int r = 0; r < 4; ++r) {
                float v = acc[mt][nt][r] + bv;
                if constexpr (EPI == 1) v = 0.5f * v * (1.0f + erff(v * 0.70710678118654752f));
                eps[(rb + r) * 68 + nt * 16 + col] = v;
            }
        }
        // wave-private region: DS ops in-order per wave; no barrier needed
#pragma unroll
        for (int j = 0; j < 2; ++j) {
            const int r  = (lane >> 3) + 8 * j;
            const int cb = (lane & 7) * 8;
            const floatx4 f0 = *(const floatx4*)&eps[r * 68 + cb];
            const floatx4 f1 = *(const floatx4*)&eps[r * 68 + cb + 4];
            const int gr = gr0 + r;
            if (gr >= M) continue;
            float rbv = 0.0f;
            if constexpr (EPI == 3) rbv = bias[gr];
            short8 o;
            if constexpr (EPI == 2) {
                const short8 rr = *(const short8*)&R[(long long)gr * ldr + gc0 + cb];
#pragma unroll
                for (int i = 0; i < 4; ++i) {
                    o[i]     = f2s(f0[i] + s2f(rr[i]));
                    o[4 + i] = f2s(f1[i] + s2f(rr[4 + i]));
                }
            } else {
#pragma unroll
                for (int i = 0; i < 4; ++i) {
                    o[i]     = f2s(f0[i] + rbv);
                    o[4 + i] = f2s(f1[i] + rbv);
                }
            }
            *(short8*)&C[(long long)gr * ldc + gc0 + cb] = o;
        }
    }
}

// ---------------------------------------------------------------------------
// Transpose-convert: out_bf16[z][n][k] = f2s(in_f32[z][k][n]). K,N mult of 32.
// block (32,8), grid (N/32, K/32, Z).
// ---------------------------------------------------------------------------
__global__ void tconv_k(const float* __restrict__ in, short* __restrict__ out,
                        int K, int N, long long inZ, long long outZ)
{
    __shared__ float t[32][33];
    in  += (long long)blockIdx.z * inZ;
    out += (long long)blockIdx.z * outZ;
    const int n0 = blockIdx.x * 32, k0 = blockIdx.y * 32;
    const int tx = threadIdx.x, ty = threadIdx.y;
#pragma unroll
    for (int i = 0; i < 4; ++i)
        t[ty + i * 8][tx] = in[(long long)(k0 + ty + i * 8) * N + n0 + tx];
    __syncthreads();
#pragma unroll
    for (int i = 0; i < 4; ++i)
        out[(long long)(n0 + ty + i * 8) * K + k0 + tx] = f2s(t[tx][ty + i * 8]);
}

// x fp32 -> bf16 flat
__global__ __launch_bounds__(256) void cvtx_k(const float* __restrict__ x,
                                              short* __restrict__ xb, int n)
{
    const int i = blockIdx.x * 256 + threadIdx.x;
    if (i < n) xb[i] = f2s(x[i]);
}

// concat per-layer q/k biases -> [12][1536] fp32
__global__ __launch_bounds__(256) void bqk_k(
    const float* __restrict__ bq, const float* __restrict__ bk,
    float* __restrict__ out)
{
    const int i = blockIdx.x * 256 + threadIdx.x;
    if (i >= 12 * 1536) return;
    const int l = i / 1536, j = i % 1536;
    out[i] = (j < 768) ? bq[l * 768 + j] : bk[l * 768 + j - 768];
}

// ---------------------------------------------------------------------------
// assemble: H[b][t][d] = (t==0 ? cls[d] : P[b*196+t-1][d]) + pos[t][d]
// ---------------------------------------------------------------------------
__global__ __launch_bounds__(256) void assemble_k(
    const short* __restrict__ P, const float* __restrict__ cls,
    const float* __restrict__ pos, short* __restrict__ H)
{
    const long long idx = (long long)blockIdx.x * 256 + threadIdx.x;
    if (idx >= 32LL * 197 * 768) return;
    const int d = (int)(idx % 768);
    const int t = (int)((idx / 768) % 197);
    const long long b = idx / (768LL * 197);
    float v = (t == 0) ? cls[d] : s2f(P[(b * 196 + t - 1) * 768 + d]);
    v += pos[t * 768 + d];
    H[idx] = f2s(v);
}

// ---------------------------------------------------------------------------
// softmax on padded S: row blockIdx = b*197+t; data at S[(b*256+t)*256].
// Reads cols 0..196, writes 0..255 (pad cols = 0 so PV's K=256 pad is exact).
// ---------------------------------------------------------------------------
__global__ __launch_bounds__(256) void softmax2_k(short* __restrict__ S, float scale)
{
    const int b = blockIdx.x / 197, t = blockIdx.x % 197;
    short* s = S + ((long long)b * 256 + t) * 256;
    const int tid = threadIdx.x;
    __shared__ float red[256];

    float x = 0.0f, v = -1e30f;
    if (tid < 197) { x = s2f(s[tid]) * scale; v = x; }
    red[tid] = v;
    __syncthreads();
    for (int st = 128; st > 0; st >>= 1) {
        if (tid < st) red[tid] = fmaxf(red[tid], red[tid + st]);
        __syncthreads();
    }
    const float mx = red[0];
    __syncthreads();
    const float e = (tid < 197) ? expf(x - mx) : 0.0f;
    red[tid] = e;
    __syncthreads();
    for (int st = 128; st > 0; st >>= 1) {
        if (tid < st) red[tid] += red[tid + st];
        __syncthreads();
    }
    const float inv = 1.0f / red[0];
    s[tid] = (tid < 197) ? f2s(e * inv) : (short)0;
}

// ---------------------------------------------------------------------------
// wave-per-row LayerNorm over 768 (shuffle reduce, no LDS). 4 rows/block.
// ---------------------------------------------------------------------------
__global__ __launch_bounds__(256) void lnw_k(
    const short* __restrict__ X, long long xs,
    short* __restrict__ Y, long long ys,
    const float* __restrict__ g, const float* __restrict__ be, int nrows)
{
    const int row  = blockIdx.x * 4 + (threadIdx.x >> 6);
    const int lane = threadIdx.x & 63;
    if (row >= nrows) return;
    const short* x = X + (long long)row * xs;
    short* y = Y + (long long)row * ys;

    float v[12], s = 0.0f, sq = 0.0f;
#pragma unroll
    for (int i = 0; i < 12; ++i) {
        const float t = s2f(x[lane + 64 * i]);
        v[i] = t; s += t; sq += t * t;
    }
#pragma unroll
    for (int m = 1; m < 64; m <<= 1) {
        s  += __shfl_xor(s,  m, 64);
        sq += __shfl_xor(sq, m, 64);
    }
    const float mean = s * (1.0f / 768.0f);
    const float var  = sq * (1.0f / 768.0f) - mean * mean;
    const float rs   = rsqrtf(var + 1e-5f);
#pragma unroll
    for (int i = 0; i < 12; ++i) {
        const int d = lane + 64 * i;
        y[d] = f2s((v[i] - mean) * rs * g[d] + be[d]);
    }
}

// ---------------------------------------------------------------------------
// head: out[b][c] = hc[b] . W[:,c] + hb[c], fp32 W/out. grid (4,32).
// ---------------------------------------------------------------------------
__global__ __launch_bounds__(256) void head2_k(
    const short* __restrict__ hc, const float* __restrict__ W,
    const float* __restrict__ hb, float* __restrict__ out)
{
    const int b = blockIdx.y;
    const int c = blockIdx.x * 256 + threadIdx.x;
    __shared__ float h[768];
    for (int i = threadIdx.x; i < 768; i += 256) h[i] = s2f(hc[b * 768 + i]);
    __syncthreads();
    if (c >= 1000) return;
    float acc = hb[c];
    for (int k = 0; k < 768; ++k) acc += h[k] * W[k * 1000 + c];
    out[b * 1000 + c] = acc;
}

// ---------------------------------------------------------------------------
extern "C" void kernel_launch(void* const* d_in, const int* in_sizes, int n_in,
                              void* d_out, int out_size, void* d_ws, size_t ws_size,
                              hipStream_t stream)
{
    const float* x     = (const float*)d_in[0];
    const float* cls   = (const float*)d_in[1];
    const float* emb_w = (const float*)d_in[2];
    const float* emb_b = (const float*)d_in[3];
    const float* pos   = (const float*)d_in[4];
    const float* Wq    = (const float*)d_in[5];
    const float* bq    = (const float*)d_in[6];
    const float* Wk    = (const float*)d_in[7];
    const float* bk    = (const float*)d_in[8];
    const float* Wv    = (const float*)d_in[9];
    const float* bv    = (const float*)d_in[10];
    const float* Wo    = (const float*)d_in[11];
    const float* bo    = (const float*)d_in[12];
    const float* g1    = (const float*)d_in[13];
    const float* be1   = (const float*)d_in[14];
    const float* W1    = (const float*)d_in[15];
    const float* b1    = (const float*)d_in[16];
    const float* W2    = (const float*)d_in[17];
    const float* b2    = (const float*)d_in[18];
    const float* g2    = (const float*)d_in[19];
    const float* be2   = (const float*)d_in[20];
    const float* fg    = (const float*)d_in[21];
    const float* fb    = (const float*)d_in[22];
    const float* hw    = (const float*)d_in[23];
    const float* hb    = (const float*)d_in[24];

    // ---- workspace layout (aliases: VT<->T1, xb<->S; both proven disjoint
    // in time: T1 dead before VT of next layer; xb dead before first S) ----
    char* ws = (char*)d_ws;
    long long o = 0;
    short* WtQK = (short*)(ws + o); o += 12LL * 1536 * 768 * 2;   // 28.3 MB
    short* WtV  = (short*)(ws + o); o += 12LL * 768 * 768 * 2;    // WvT [d][k]
    short* WtO  = (short*)(ws + o); o += 12LL * 768 * 768 * 2;
    short* Wt1  = (short*)(ws + o); o += 12LL * 768 * 768 * 2;
    short* Wt2  = (short*)(ws + o); o += 12LL * 768 * 768 * 2;
    short* embT = (short*)(ws + o); o += 768LL * 256 * 2;
    short* H    = (short*)(ws + o); o += 6400LL * 768 * 2;
    short* QKVb = (short*)(ws + o); o += 6400LL * 1536 * 2;       // Q|K slab
    short* AO   = (short*)(ws + o); o += 6400LL * 768 * 2;
    short* VT   = (short*)(ws + o); o += 32LL * 768 * 256 * 2;    // 12.58 MB
    short* T1   = VT;                                             // alias
    short* S    = (short*)(ws + o); o += 32LL * 256 * 256 * 2;    // 4.19 MB
    short* xb   = S;                                              // alias
    short* hc   = (short*)(ws + o); o += 32LL * 768 * 2;
    float* bqk  = (float*)(ws + o); o += 12LL * 1536 * 4;

    const dim3 blk(256);
    const dim3 tblk(32, 8);
    const float scale = 0.03608439182435161f;  // 768^-0.5
    const long long sH  = 197LL * 768;    // H batch stride
    const long long sQK = 197LL * 1536;   // QKVb batch stride
    const long long sS  = 256LL * 256;    // padded S batch stride
    const long long sVT = 768LL * 256;    // VT batch stride

    // ---- prep ----
    tconv_k<<<dim3(24, 8, 1),   tblk, 0, stream>>>(emb_w, embT, 256, 768, 0, 0);
    tconv_k<<<dim3(24, 24, 12), tblk, 0, stream>>>(Wq, WtQK,             768, 768, 589824, 1536LL * 768);
    tconv_k<<<dim3(24, 24, 12), tblk, 0, stream>>>(Wk, WtQK + 768 * 768, 768, 768, 589824, 1536LL * 768);
    tconv_k<<<dim3(24, 24, 12), tblk, 0, stream>>>(Wv, WtV, 768, 768, 589824, 589824);
    tconv_k<<<dim3(24, 24, 12), tblk, 0, stream>>>(Wo, WtO, 768, 768, 589824, 589824);
    tconv_k<<<dim3(24, 24, 12), tblk, 0, stream>>>(W1, Wt1, 768, 768, 589824, 589824);
    tconv_k<<<dim3(24, 24, 12), tblk, 0, stream>>>(W2, Wt2, 768, 768, 589824, 589824);
    cvtx_k<<<dim3(6272), blk, 0, stream>>>(x, xb, 6272 * 256);
    bqk_k<<<dim3(72), blk, 0, stream>>>(bq, bk, bqk);

    // ---- patch embed + assemble ----
    gemm128<0><<<dim3(49, 6), blk, 0, stream>>>(
        xb, 0, 256, embT, 0, 256, emb_b, nullptr, 0, T1, 0, 768, 6272, 768, 256);
    assemble_k<<<dim3((32 * 197 * 768 + 255) / 256), blk, 0, stream>>>(T1, cls, pos, H);

    for (int l = 0; l < 12; ++l) {
        const long long w1o = (long long)l * 589824;
        const long long vo  = (long long)l * 768;
        // QK: [6304][1536]
        gemm128<0><<<dim3(50, 12), blk, 0, stream>>>(
            H, 0, 768, WtQK + (long long)l * 1536 * 768, 0, 768, bqk + l * 1536,
            nullptr, 0, QKVb, 0, 1536, 6304, 1536, 768);
        // VT[b][d][t] = WvT @ H[b]^T + bv (row bias), t padded to 256
        gemm128<3><<<dim3(6, 2, 32), blk, 0, stream>>>(
            WtV + w1o, 0, 768, H, sH, 768, bv + vo,
            nullptr, 0, VT, sVT, 256, 768, 256, 768);
        // S[b] = Q[b] @ K[b]^T  [197(pad256)][256]
        gemm128<0><<<dim3(2, 2, 32), blk, 0, stream>>>(
            QKVb, sQK, 1536, QKVb + 768, sQK, 1536, nullptr,
            nullptr, 0, S, sS, 256, 197, 256, 768);
        softmax2_k<<<dim3(32 * 197), blk, 0, stream>>>(S, scale);
        // AO[b] = P[b] @ VT[b]^T   (K=256, pad cols of P are 0)
        gemm128<0><<<dim3(2, 6, 32), blk, 0, stream>>>(
            S, sS, 256, VT, sVT, 256, nullptr,
            nullptr, 0, AO, sH, 768, 197, 768, 256);
        // T1 = AO @ Wo + bo + H ; H = LN(T1)
        gemm128<2><<<dim3(50, 6), blk, 0, stream>>>(
            AO, 0, 768, WtO + w1o, 0, 768, bo + vo, H, 768, T1, 0, 768, 6304, 768, 768);
        lnw_k<<<dim3(1576), blk, 0, stream>>>(T1, 768, H, 768, g1 + vo, be1 + vo, 6304);
        // T1 = gelu(H @ W1 + b1) ; AO = T1 @ W2 + b2 + H ; H = LN(AO)
        gemm128<1><<<dim3(50, 6), blk, 0, stream>>>(
            H, 0, 768, Wt1 + w1o, 0, 768, b1 + vo, nullptr, 0, T1, 0, 768, 6304, 768, 768);
        gemm128<2><<<dim3(50, 6), blk, 0, stream>>>(
            T1, 0, 768, Wt2 + w1o, 0, 768, b2 + vo, H, 768, AO, 0, 768, 6304, 768, 768);
        lnw_k<<<dim3(1576), blk, 0, stream>>>(AO, 768, H, 768, g2 + vo, be2 + vo, 6304);
    }

    // final LN on cls tokens (stride 197*768) + head
    lnw_k<<<dim3(8), blk, 0, stream>>>(H, sH, hc, 768, fg, fb, 32);
    head2_k<<<dim3(4, 32), blk, 0, stream>>>(hc, hw, hb, (float*)d_out);
}

// Round 7
// 2418.518 us; speedup vs baseline: 3.5442x; 1.0723x over previous
//
#include <hip/hip_runtime.h>
#include <hip/hip_bf16.h>
#include <math.h>

typedef short short8 __attribute__((ext_vector_type(8)));
typedef float floatx4 __attribute__((ext_vector_type(4)));

#define DEV static __device__ __forceinline__

DEV float s2f(short v) {
    unsigned int u = ((unsigned int)(unsigned short)v) << 16;
    float f;
    __builtin_memcpy(&f, &u, 4);
    return f;
}
DEV short f2s(float f) {
    __hip_bfloat16 b = __float2bfloat16(f);   // RNE
    short s;
    __builtin_memcpy(&s, &b, 2);
    return s;
}

DEV void async_copy16(const void* g, void* l) {
    __builtin_amdgcn_global_load_lds(
        (const __attribute__((address_space(1))) void*)g,
        (__attribute__((address_space(3))) void*)l, 16, 0, 0);
}

// ---------------------------------------------------------------------------
// gemm64: 64(M)x128(N) tile, BK=64 as two 32-k panels, global_load_lds 16B.
// C[M][N] = epi(A @ Bt^T [+bias] [+R]), z-batched. N mult 128, K mult 64.
// 4 waves in 2x2: each wave 32x64 (2 m-frags x 4 n-frags of 16x16x32 MFMA).
// EPI: 0 plain(+col bias), 1 GELU(+col bias), 2 +col bias +residual,
//      3 +row bias (for V^T).
// smem: A panels [0,4096) shorts, B panels [4096,12288) shorts (24 KB).
// ---------------------------------------------------------------------------
struct GP {
    const short* A;  long long zA; int lda;
    const short* Bt; long long zB; int ldb;
    const float* bias;
    const short* R;  int ldr;
    short* C;        long long zC; int ldc;
    int M, N, K;
};

template<int EPI>
DEV void gemm_body(short* smem, const GP p, int bx, int by, int bz)
{
    const short* A  = p.A  + (long long)bz * p.zA;
    const short* Bt = p.Bt + (long long)bz * p.zB;
    short* C        = p.C  + (long long)bz * p.zC;

    const int tid   = threadIdx.x;
    const int lane  = tid & 63;
    const int wave  = tid >> 6;
    const int tileM = bx * 64;
    const int tileN = by * 128;
    const int wm    = (wave & 1) * 32;
    const int wn    = (wave >> 1) * 64;

    floatx4 acc[2][4];
#pragma unroll
    for (int mt = 0; mt < 2; ++mt)
#pragma unroll
        for (int nt = 0; nt < 4; ++nt)
            acc[mt][nt] = (floatx4){0.f, 0.f, 0.f, 0.f};

    for (int k0 = 0; k0 < p.K; k0 += 64) {
#pragma unroll
        for (int h = 0; h < 2; ++h) {
            {   // A panel 64x32: 256 16B chunks, 1/thread
                const int c   = tid;
                const int row = c >> 2;
                const int ko  = (c & 3) * 8;
                async_copy16(A + (long long)(tileM + row) * p.lda + k0 + h * 32 + ko,
                             &smem[h * 2048 + c * 8]);
            }
#pragma unroll
            for (int i = 0; i < 2; ++i) {   // B panel 128x32: 512 chunks, 2/thread
                const int c   = i * 256 + tid;
                const int row = c >> 2;
                const int ko  = (c & 3) * 8;
                async_copy16(Bt + (long long)(tileN + row) * p.ldb + k0 + h * 32 + ko,
                             &smem[4096 + h * 4096 + c * 8]);
            }
        }
        __syncthreads();

        const int fr = lane & 15;
        const int ko = (lane >> 4) * 8;
#pragma unroll
        for (int h = 0; h < 2; ++h) {
            const short* pA = &smem[h * 2048];
            const short* pB = &smem[4096 + h * 4096];
            short8 af[2], bf[4];
#pragma unroll
            for (int t = 0; t < 2; ++t)
                af[t] = *(const short8*)&pA[(wm + fr + t * 16) * 32 + ko];
#pragma unroll
            for (int t = 0; t < 4; ++t)
                bf[t] = *(const short8*)&pB[(wn + fr + t * 16) * 32 + ko];
#pragma unroll
            for (int mt = 0; mt < 2; ++mt)
#pragma unroll
                for (int nt = 0; nt < 4; ++nt)
                    acc[mt][nt] = __builtin_amdgcn_mfma_f32_16x16x32_bf16(
                        af[mt], bf[nt], acc[mt][nt], 0, 0, 0);
        }
        __syncthreads();
    }

    // ---- epilogue: wave-private fp32 LDS stage -> coalesced short8 stores ----
    float* eps = (float*)smem + wave * (16 * 68);
    const int col = lane & 15;
    const int rb  = (lane >> 4) * 4;
#pragma unroll
    for (int mt = 0; mt < 2; ++mt) {
        const int gr0 = tileM + wm + mt * 16;
        const int gc0 = tileN + wn;
#pragma unroll
        for (int nt = 0; nt < 4; ++nt) {
            float bv = 0.0f;
            if constexpr (EPI != 3) { if (p.bias) bv = p.bias[gc0 + nt * 16 + col]; }
#pragma unroll
            for (int r = 0; r < 4; ++r) {
                float v = acc[mt][nt][r] + bv;
                if constexpr (EPI == 1) v = 0.5f * v * (1.0f + erff(v * 0.70710678118654752f));
                eps[(rb + r) * 68 + nt * 16 + col] = v;
            }
        }
        // wave-private region; DS ops in-order per wave — no barrier needed
#pragma unroll
        for (int j = 0; j < 2; ++j) {
            const int r  = (lane >> 3) + 8 * j;
            const int cb = (lane & 7) * 8;
            const floatx4 f0 = *(const floatx4*)&eps[r * 68 + cb];
            const floatx4 f1 = *(const floatx4*)&eps[r * 68 + cb + 4];
            const int gr = gr0 + r;
            if (gr >= p.M) continue;
            float rbv = 0.0f;
            if constexpr (EPI == 3) rbv = p.bias[gr];
            short8 o;
            if constexpr (EPI == 2) {
                const short8 rr = *(const short8*)&p.R[(long long)gr * p.ldr + gc0 + cb];
#pragma unroll
                for (int i = 0; i < 4; ++i) {
                    o[i]     = f2s(f0[i] + s2f(rr[i]));
                    o[4 + i] = f2s(f1[i] + s2f(rr[4 + i]));
                }
            } else {
#pragma unroll
                for (int i = 0; i < 4; ++i) {
                    o[i]     = f2s(f0[i] + rbv);
                    o[4 + i] = f2s(f1[i] + rbv);
                }
            }
            *(short8*)&C[(long long)gr * p.ldc + gc0 + cb] = o;
        }
    }
}

template<int EPI>
__global__ __launch_bounds__(256) void gemm64_k(GP p)
{
    __shared__ short smem[12288];
    gemm_body<EPI>(smem, p, blockIdx.x, blockIdx.y, blockIdx.z);
}

// Combined QK (EPI 0) + VT (EPI 3) dispatch: flat 1-D grid, block-level branch.
__global__ __launch_bounds__(256) void qkvt_k(GP qk, GP vt, int nQK)
{
    __shared__ short smem[12288];
    const int id = blockIdx.x;
    if (id < nQK) {
        gemm_body<0>(smem, qk, id % 99, id / 99, 0);
    } else {
        const int i2 = id - nQK;               // VT: 12 x-tiles, 2 y, 32 z
        gemm_body<3>(smem, vt, i2 % 12, (i2 / 12) % 2, i2 / 24);
    }
}

// ---------------------------------------------------------------------------
// Transpose-convert: out_bf16[z][n][k] = f2s(in_f32[z][k][n]). K,N mult of 32.
// ---------------------------------------------------------------------------
__global__ void tconv_k(const float* __restrict__ in, short* __restrict__ out,
                        int K, int N, long long inZ, long long outZ)
{
    __shared__ float t[32][33];
    in  += (long long)blockIdx.z * inZ;
    out += (long long)blockIdx.z * outZ;
    const int n0 = blockIdx.x * 32, k0 = blockIdx.y * 32;
    const int tx = threadIdx.x, ty = threadIdx.y;
#pragma unroll
    for (int i = 0; i < 4; ++i)
        t[ty + i * 8][tx] = in[(long long)(k0 + ty + i * 8) * N + n0 + tx];
    __syncthreads();
#pragma unroll
    for (int i = 0; i < 4; ++i)
        out[(long long)(n0 + ty + i * 8) * K + k0 + tx] = f2s(t[tx][ty + i * 8]);
}

// x fp32 -> bf16 flat
__global__ __launch_bounds__(256) void cvtx_k(const float* __restrict__ x,
                                              short* __restrict__ xb, int n)
{
    const int i = blockIdx.x * 256 + threadIdx.x;
    if (i < n) xb[i] = f2s(x[i]);
}

// concat per-layer q/k biases -> [12][1536] fp32
__global__ __launch_bounds__(256) void bqk_k(
    const float* __restrict__ bq, const float* __restrict__ bk,
    float* __restrict__ out)
{
    const int i = blockIdx.x * 256 + threadIdx.x;
    if (i >= 12 * 1536) return;
    const int l = i / 1536, j = i % 1536;
    out[i] = (j < 768) ? bq[l * 768 + j] : bk[l * 768 + j - 768];
}

// ---------------------------------------------------------------------------
// assemble: H[b][t][d] = (t==0 ? cls[d] : P[b*196+t-1][d]) + pos[t][d]
// ---------------------------------------------------------------------------
__global__ __launch_bounds__(256) void assemble_k(
    const short* __restrict__ P, const float* __restrict__ cls,
    const float* __restrict__ pos, short* __restrict__ H)
{
    const long long idx = (long long)blockIdx.x * 256 + threadIdx.x;
    if (idx >= 32LL * 197 * 768) return;
    const int d = (int)(idx % 768);
    const int t = (int)((idx / 768) % 197);
    const long long b = idx / (768LL * 197);
    float v = (t == 0) ? cls[d] : s2f(P[(b * 196 + t - 1) * 768 + d]);
    v += pos[t * 768 + d];
    H[idx] = f2s(v);
}

// ---------------------------------------------------------------------------
// softmax on padded S: row blockIdx = b*197+t; data at S[(b*256+t)*256].
// Reads cols 0..196, writes 0..255 (pad cols = 0 so PV's K=256 pad is exact).
// ---------------------------------------------------------------------------
__global__ __launch_bounds__(256) void softmax2_k(short* __restrict__ S, float scale)
{
    const int b = blockIdx.x / 197, t = blockIdx.x % 197;
    short* s = S + ((long long)b * 256 + t) * 256;
    const int tid = threadIdx.x;
    __shared__ float red[256];

    float x = 0.0f, v = -1e30f;
    if (tid < 197) { x = s2f(s[tid]) * scale; v = x; }
    red[tid] = v;
    __syncthreads();
    for (int st = 128; st > 0; st >>= 1) {
        if (tid < st) red[tid] = fmaxf(red[tid], red[tid + st]);
        __syncthreads();
    }
    const float mx = red[0];
    __syncthreads();
    const float e = (tid < 197) ? expf(x - mx) : 0.0f;
    red[tid] = e;
    __syncthreads();
    for (int st = 128; st > 0; st >>= 1) {
        if (tid < st) red[tid] += red[tid + st];
        __syncthreads();
    }
    const float inv = 1.0f / red[0];
    s[tid] = (tid < 197) ? f2s(e * inv) : (short)0;
}

// ---------------------------------------------------------------------------
// wave-per-row LayerNorm over 768 (shuffle reduce). 4 rows/block.
// ---------------------------------------------------------------------------
__global__ __launch_bounds__(256) void lnw_k(
    const short* __restrict__ X, long long xs,
    short* __restrict__ Y, long long ys,
    const float* __restrict__ g, const float* __restrict__ be, int nrows)
{
    const int row  = blockIdx.x * 4 + (threadIdx.x >> 6);
    const int lane = threadIdx.x & 63;
    if (row >= nrows) return;
    const short* x = X + (long long)row * xs;
    short* y = Y + (long long)row * ys;

    float v[12], s = 0.0f, sq = 0.0f;
#pragma unroll
    for (int i = 0; i < 12; ++i) {
        const float t = s2f(x[lane + 64 * i]);
        v[i] = t; s += t; sq += t * t;
    }
#pragma unroll
    for (int m = 1; m < 64; m <<= 1) {
        s  += __shfl_xor(s,  m, 64);
        sq += __shfl_xor(sq, m, 64);
    }
    const float mean = s * (1.0f / 768.0f);
    const float var  = sq * (1.0f / 768.0f) - mean * mean;
    const float rs   = rsqrtf(var + 1e-5f);
#pragma unroll
    for (int i = 0; i < 12; ++i) {
        const int d = lane + 64 * i;
        y[d] = f2s((v[i] - mean) * rs * g[d] + be[d]);
    }
}

// ---------------------------------------------------------------------------
// head3: out[b][c] = hc[b].W[:,c] + hb[c]; split-k x4 + LDS reduce.
// grid (16, 32); block 256 = 64 cols x 4 k-slices. fp32 W, fp32 out.
// ---------------------------------------------------------------------------
__global__ __launch_bounds__(256) void head3_k(
    const short* __restrict__ hc, const float* __restrict__ W,
    const float* __restrict__ hb, float* __restrict__ out)
{
    const int b  = blockIdx.y;
    const int cc = threadIdx.x & 63;
    const int ks = threadIdx.x >> 6;
    const int c  = blockIdx.x * 64 + cc;
    __shared__ float h[768];
    __shared__ float red[4][64];
    for (int i = threadIdx.x; i < 768; i += 256) h[i] = s2f(hc[b * 768 + i]);
    __syncthreads();
    float acc = 0.0f;
    if (c < 1000) {
        const int k0 = ks * 192;
        for (int k = k0; k < k0 + 192; ++k) acc += h[k] * W[k * 1000 + c];
    }
    red[ks][cc] = acc;
    __syncthreads();
    if (ks == 0 && c < 1000)
        out[b * 1000 + c] = red[0][cc] + red[1][cc] + red[2][cc] + red[3][cc] + hb[c];
}

// ---------------------------------------------------------------------------
extern "C" void kernel_launch(void* const* d_in, const int* in_sizes, int n_in,
                              void* d_out, int out_size, void* d_ws, size_t ws_size,
                              hipStream_t stream)
{
    const float* x     = (const float*)d_in[0];
    const float* cls   = (const float*)d_in[1];
    const float* emb_w = (const float*)d_in[2];
    const float* emb_b = (const float*)d_in[3];
    const float* pos   = (const float*)d_in[4];
    const float* Wq    = (const float*)d_in[5];
    const float* bq    = (const float*)d_in[6];
    const float* Wk    = (const float*)d_in[7];
    const float* bk    = (const float*)d_in[8];
    const float* Wv    = (const float*)d_in[9];
    const float* bv    = (const float*)d_in[10];
    const float* Wo    = (const float*)d_in[11];
    const float* bo    = (const float*)d_in[12];
    const float* g1    = (const float*)d_in[13];
    const float* be1   = (const float*)d_in[14];
    const float* W1    = (const float*)d_in[15];
    const float* b1    = (const float*)d_in[16];
    const float* W2    = (const float*)d_in[17];
    const float* b2    = (const float*)d_in[18];
    const float* g2    = (const float*)d_in[19];
    const float* be2   = (const float*)d_in[20];
    const float* fg    = (const float*)d_in[21];
    const float* fb    = (const float*)d_in[22];
    const float* hw    = (const float*)d_in[23];
    const float* hb    = (const float*)d_in[24];

    char* ws = (char*)d_ws;
    long long o = 0;
    short* WtQK = (short*)(ws + o); o += 12LL * 1536 * 768 * 2;
    short* WtV  = (short*)(ws + o); o += 12LL * 768 * 768 * 2;
    short* WtO  = (short*)(ws + o); o += 12LL * 768 * 768 * 2;
    short* Wt1  = (short*)(ws + o); o += 12LL * 768 * 768 * 2;
    short* Wt2  = (short*)(ws + o); o += 12LL * 768 * 768 * 2;
    short* embT = (short*)(ws + o); o += 768LL * 256 * 2;
    short* H    = (short*)(ws + o); o += 6400LL * 768 * 2;
    short* QKVb = (short*)(ws + o); o += 6400LL * 1536 * 2;
    short* AO   = (short*)(ws + o); o += 6400LL * 768 * 2;
    short* VT   = (short*)(ws + o); o += 32LL * 768 * 256 * 2;
    short* T1   = VT;                                  // alias (disjoint in time)
    short* S    = (short*)(ws + o); o += 32LL * 256 * 256 * 2;
    short* xb   = S;                                   // alias (disjoint in time)
    short* hc   = (short*)(ws + o); o += 64LL * 768 * 2;
    float* bqk  = (float*)(ws + o); o += 12LL * 1536 * 4;

    const dim3 blk(256);
    const dim3 tblk(32, 8);
    const float scale = 0.03608439182435161f;  // 768^-0.5
    const long long sH  = 197LL * 768;
    const long long sQK = 197LL * 1536;
    const long long sS  = 256LL * 256;
    const long long sVT = 768LL * 256;

    // ---- prep ----
    tconv_k<<<dim3(24, 8, 1),   tblk, 0, stream>>>(emb_w, embT, 256, 768, 0, 0);
    tconv_k<<<dim3(24, 24, 12), tblk, 0, stream>>>(Wq, WtQK,             768, 768, 589824, 1536LL * 768);
    tconv_k<<<dim3(24, 24, 12), tblk, 0, stream>>>(Wk, WtQK + 768 * 768, 768, 768, 589824, 1536LL * 768);
    tconv_k<<<dim3(24, 24, 12), tblk, 0, stream>>>(Wv, WtV, 768, 768, 589824, 589824);
    tconv_k<<<dim3(24, 24, 12), tblk, 0, stream>>>(Wo, WtO, 768, 768, 589824, 589824);
    tconv_k<<<dim3(24, 24, 12), tblk, 0, stream>>>(W1, Wt1, 768, 768, 589824, 589824);
    tconv_k<<<dim3(24, 24, 12), tblk, 0, stream>>>(W2, Wt2, 768, 768, 589824, 589824);
    cvtx_k<<<dim3(6272), blk, 0, stream>>>(x, xb, 6272 * 256);
    bqk_k<<<dim3(72), blk, 0, stream>>>(bq, bk, bqk);

    // ---- patch embed + assemble ----
    {
        GP p = { xb, 0, 256, embT, 0, 256, emb_b, nullptr, 0, T1, 0, 768, 6272, 768, 256 };
        gemm64_k<0><<<dim3(98, 6), blk, 0, stream>>>(p);
    }
    assemble_k<<<dim3((32 * 197 * 768 + 255) / 256), blk, 0, stream>>>(T1, cls, pos, H);

    for (int l = 0; l < 12; ++l) {
        const long long w1o = (long long)l * 589824;
        const long long vo  = (long long)l * 768;
        // QK [6304][1536] + VT[b][d][t] in ONE dispatch (1188 + 768 blocks)
        {
            GP qk = { H, 0, 768, WtQK + (long long)l * 1536 * 768, 0, 768,
                      bqk + l * 1536, nullptr, 0, QKVb, 0, 1536, 6304, 1536, 768 };
            GP vt = { WtV + w1o, 0, 768, H, sH, 768, bv + vo,
                      nullptr, 0, VT, sVT, 256, 768, 256, 768 };
            qkvt_k<<<dim3(1188 + 768), blk, 0, stream>>>(qk, vt, 1188);
        }
        // S[b] = Q[b] @ K[b]^T  [197(pad256)][256]
        {
            GP p = { QKVb, sQK, 1536, QKVb + 768, sQK, 1536, nullptr,
                     nullptr, 0, S, sS, 256, 197, 256, 768 };
            gemm64_k<0><<<dim3(4, 2, 32), blk, 0, stream>>>(p);
        }
        softmax2_k<<<dim3(32 * 197), blk, 0, stream>>>(S, scale);
        // AO[b] = P[b] @ VT[b]^T   (K=256; pad cols of P are 0)
        {
            GP p = { S, sS, 256, VT, sVT, 256, nullptr,
                     nullptr, 0, AO, sH, 768, 197, 768, 256 };
            gemm64_k<0><<<dim3(4, 6, 32), blk, 0, stream>>>(p);
        }
        // T1 = AO @ Wo + bo + H ; H = LN(T1)
        {
            GP p = { AO, 0, 768, WtO + w1o, 0, 768, bo + vo, H, 768,
                     T1, 0, 768, 6304, 768, 768 };
            gemm64_k<2><<<dim3(99, 6), blk, 0, stream>>>(p);
        }
        lnw_k<<<dim3(1576), blk, 0, stream>>>(T1, 768, H, 768, g1 + vo, be1 + vo, 6304);
        // T1 = gelu(H @ W1 + b1) ; AO = T1 @ W2 + b2 + H ; H = LN(AO)
        {
            GP p = { H, 0, 768, Wt1 + w1o, 0, 768, b1 + vo, nullptr, 0,
                     T1, 0, 768, 6304, 768, 768 };
            gemm64_k<1><<<dim3(99, 6), blk, 0, stream>>>(p);
        }
        {
            GP p = { T1, 0, 768, Wt2 + w1o, 0, 768, b2 + vo, H, 768,
                     AO, 0, 768, 6304, 768, 768 };
            gemm64_k<2><<<dim3(99, 6), blk, 0, stream>>>(p);
        }
        lnw_k<<<dim3(1576), blk, 0, stream>>>(AO, 768, H, 768, g2 + vo, be2 + vo, 6304);
    }

    // final LN on cls tokens (stride 197*768) + head
    lnw_k<<<dim3(8), blk, 0, stream>>>(H, sH, hc, 768, fg, fb, 32);
    head3_k<<<dim3(16, 32), blk, 0, stream>>>(hc, hw, hb, (float*)d_out);
}